// Round 2
// baseline (713.576 us; speedup 1.0000x reference)
//
#include <hip/hip_runtime.h>

// ---------------------------------------------------------------------------
// DCINet: 3-layer GraphSAGE (mean aggr) + degree embedding encoder + MLP head.
// N=50000, E=800000, H=128. All fp32 (threshold ~3.4e-4 forbids bf16 chain).
// Structure per call (deterministic): CSR build -> encoder -> 3x(agg, gemm) -> head.
// ---------------------------------------------------------------------------

#define HDIM 128

// ---- CSR build ------------------------------------------------------------

__global__ void count_kernel(const int* __restrict__ src, const int* __restrict__ dst,
                             int* __restrict__ indeg, int* __restrict__ outdeg, int E) {
    int e = blockIdx.x * blockDim.x + threadIdx.x;
    if (e < E) {
        atomicAdd(&indeg[dst[e]], 1);
        atomicAdd(&outdeg[src[e]], 1);
    }
}

// single-block exclusive scan over n elements (n ~ 50000, 49 chunks of 1024)
__global__ void scan_kernel(const int* __restrict__ indeg, int* __restrict__ row_ptr, int n) {
    __shared__ int sh[1024];
    __shared__ int s_carry;
    const int tid = threadIdx.x;
    if (tid == 0) s_carry = 0;
    __syncthreads();
    for (int base = 0; base < n; base += 1024) {
        int i = base + tid;
        int v = (i < n) ? indeg[i] : 0;
        sh[tid] = v;
        __syncthreads();
        for (int off = 1; off < 1024; off <<= 1) {
            int t = (tid >= off) ? sh[tid - off] : 0;
            __syncthreads();
            sh[tid] += t;
            __syncthreads();
        }
        int carry = s_carry;                  // safe: sync'd after last write
        if (i < n) row_ptr[i] = carry + sh[tid] - v;   // exclusive
        __syncthreads();
        if (tid == 1023) s_carry = carry + sh[1023];
        __syncthreads();
    }
    if (tid == 0) row_ptr[n] = s_carry;
}

__global__ void fill_kernel(const int* __restrict__ src, const int* __restrict__ dst,
                            const int* __restrict__ row_ptr, int* __restrict__ fill,
                            int* __restrict__ csr, int E) {
    int e = blockIdx.x * blockDim.x + threadIdx.x;
    if (e < E) {
        int d = dst[e];
        int pos = atomicAdd(&fill[d], 1);
        csr[row_ptr[d] + pos] = src[e];
    }
}

// ---- tiny weight transpose: in [R][C] -> out [C][R] -----------------------

__global__ void transpose_kernel(const float* __restrict__ in, float* __restrict__ out,
                                 int R, int C) {
    int idx = blockIdx.x * blockDim.x + threadIdx.x;
    if (idx >= R * C) return;
    int r = idx / C, c = idx % C;
    out[c * R + r] = in[idx];
}

// ---- encoder: h = relu(x*Wenc + benc + deg_emb[min(outdeg,199)]) -----------

__global__ void encoder_kernel(const float* __restrict__ x, const float* __restrict__ Wenc,
                               const float* __restrict__ benc, const float* __restrict__ demb,
                               const int* __restrict__ outdeg, float* __restrict__ h, int n) {
    int idx = blockIdx.x * blockDim.x + threadIdx.x;   // over n*32 float4s
    if (idx >= n * 32) return;
    int i = idx >> 5, c4 = idx & 31;
    int d = outdeg[i]; if (d > 199) d = 199;
    float xv = x[i];
    float4 w = ((const float4*)Wenc)[c4];
    float4 b = ((const float4*)benc)[c4];
    float4 e = ((const float4*)demb)[d * 32 + c4];
    float4 o;
    o.x = fmaxf(xv * w.x + b.x + e.x, 0.f);
    o.y = fmaxf(xv * w.y + b.y + e.y, 0.f);
    o.z = fmaxf(xv * w.z + b.z + e.z, 0.f);
    o.w = fmaxf(xv * w.w + b.w + e.w, 0.f);
    ((float4*)h)[(size_t)i * 32 + c4] = o;
}

// ---- mean aggregation: one wave per node, float2 per lane ------------------

__global__ __launch_bounds__(256) void aggregate_kernel(const float* __restrict__ hin,
                                                        const int* __restrict__ row_ptr,
                                                        const int* __restrict__ csr,
                                                        float* __restrict__ agg, int n) {
    int i = blockIdx.x * 4 + (threadIdx.x >> 6);
    if (i >= n) return;
    int lane = threadIdx.x & 63;
    int beg = row_ptr[i], end = row_ptr[i + 1];
    float ax = 0.f, ay = 0.f;
    int e = beg;
    for (; e + 1 < end; e += 2) {          // 2 edges in flight for MLP
        int s0 = csr[e], s1 = csr[e + 1];
        float2 a = *(const float2*)(hin + (size_t)s0 * HDIM + lane * 2);
        float2 b = *(const float2*)(hin + (size_t)s1 * HDIM + lane * 2);
        ax += a.x + b.x; ay += a.y + b.y;
    }
    if (e < end) {
        int s = csr[e];
        float2 a = *(const float2*)(hin + (size_t)s * HDIM + lane * 2);
        ax += a.x; ay += a.y;
    }
    float c = (float)(end - beg);
    float inv = 1.f / fmaxf(c, 1.f);
    float2 o; o.x = ax * inv; o.y = ay * inv;
    *(float2*)(agg + (size_t)i * HDIM + lane * 2) = o;
}

// ---- fused SAGE linear: out = relu(agg@WlT + hin@WrT + b) (+ hin residual) --
// 32 rows x 128 cols per block of 256 threads; thread = 4 rows x 4 cols.

template <bool RES>
__global__ __launch_bounds__(256) void gemm_sage(const float* __restrict__ agg,
                                                 const float* __restrict__ hin,
                                                 const float* __restrict__ WlT,
                                                 const float* __restrict__ WrT,
                                                 const float* __restrict__ bias,
                                                 float* __restrict__ out, int n) {
    __shared__ float sA[32][HDIM];
    __shared__ float sH[32][HDIM];
    const int t = threadIdx.x;
    const int row0 = blockIdx.x * 32;
    for (int i = t; i < 32 * 32; i += 256) {        // 1024 float4 per matrix
        int r = i >> 5, c4 = i & 31;
        int gr = row0 + r; if (gr > n - 1) gr = n - 1;
        ((float4*)(&sA[r][0]))[c4] = ((const float4*)(agg + (size_t)gr * HDIM))[c4];
        ((float4*)(&sH[r][0]))[c4] = ((const float4*)(hin + (size_t)gr * HDIM))[c4];
    }
    __syncthreads();
    const int cg = t & 31;      // cols cg*4 .. cg*4+3
    const int rg = t >> 5;      // rows rg*4 .. rg*4+3
    float acc[4][4] = {};
    for (int k = 0; k < 128; ++k) {
        float4 wl = ((const float4*)(WlT + k * HDIM))[cg];
        float4 wr = ((const float4*)(WrT + k * HDIM))[cg];
#pragma unroll
        for (int r = 0; r < 4; ++r) {
            float a = sA[rg * 4 + r][k];    // broadcast (2 addrs per wave)
            float hh = sH[rg * 4 + r][k];
            acc[r][0] += a * wl.x + hh * wr.x;
            acc[r][1] += a * wl.y + hh * wr.y;
            acc[r][2] += a * wl.z + hh * wr.z;
            acc[r][3] += a * wl.w + hh * wr.w;
        }
    }
    float4 bv = ((const float4*)bias)[cg];
#pragma unroll
    for (int r = 0; r < 4; ++r) {
        int row = row0 + rg * 4 + r;
        if (row >= n) continue;
        float4 o;
        o.x = fmaxf(acc[r][0] + bv.x, 0.f);
        o.y = fmaxf(acc[r][1] + bv.y, 0.f);
        o.z = fmaxf(acc[r][2] + bv.z, 0.f);
        o.w = fmaxf(acc[r][3] + bv.w, 0.f);
        if (RES) {
            float4 rv = ((float4*)(&sH[rg * 4 + r][0]))[cg];
            o.x += rv.x; o.y += rv.y; o.z += rv.z; o.w += rv.w;
        }
        ((float4*)(out + (size_t)row * HDIM))[cg] = o;
    }
}

// ---- head: scores[i] = relu(h3@Wh1T + bh1) @ Wh2 + bh2 ; one wave per node --

__global__ __launch_bounds__(256) void head_kernel(const float* __restrict__ h3,
                                                   const float* __restrict__ Wh1T,
                                                   const float* __restrict__ bh1,
                                                   const float* __restrict__ Wh2,
                                                   const float* __restrict__ bh2,
                                                   float* __restrict__ out, int n) {
    int i = blockIdx.x * 4 + (threadIdx.x >> 6);
    if (i >= n) return;
    int lane = threadIdx.x & 63;
    const float* hrow = h3 + (size_t)i * HDIM;
    float acc = bh1[lane];
    for (int k = 0; k < HDIM; ++k)
        acc += hrow[k] * Wh1T[k * 64 + lane];
    float z = fmaxf(acc, 0.f);
    float p = z * Wh2[lane];
#pragma unroll
    for (int off = 32; off > 0; off >>= 1) p += __shfl_down(p, off, 64);
    if (lane == 0) out[i] = p + bh2[0];
}

// ---------------------------------------------------------------------------

extern "C" void kernel_launch(void* const* d_in, const int* in_sizes, int n_in,
                              void* d_out, int out_size, void* d_ws, size_t ws_size,
                              hipStream_t stream) {
    const int N = in_sizes[0];          // x is [N,1]
    const int E = in_sizes[1] / 2;      // edge_index [2,E]
    const int H = HDIM;

    const float* x    = (const float*)d_in[0];
    const int*   ei   = (const int*)d_in[1];
    const int*   src  = ei;
    const int*   dst  = ei + E;
    const float* Wenc = (const float*)d_in[2];
    const float* benc = (const float*)d_in[3];
    const float* demb = (const float*)d_in[4];
    const float* W1l  = (const float*)d_in[5];
    const float* b1l  = (const float*)d_in[6];
    const float* W1r  = (const float*)d_in[7];
    const float* W2l  = (const float*)d_in[8];
    const float* b2l  = (const float*)d_in[9];
    const float* W2r  = (const float*)d_in[10];
    const float* W3l  = (const float*)d_in[11];
    const float* b3l  = (const float*)d_in[12];
    const float* W3r  = (const float*)d_in[13];
    const float* Wh1  = (const float*)d_in[14];
    const float* bh1  = (const float*)d_in[15];
    const float* Wh2  = (const float*)d_in[16];
    const float* bh2  = (const float*)d_in[17];

    // workspace carve (256B aligned)
    size_t off = 0;
    char* base = (char*)d_ws;
    auto carve = [&](size_t bytes) -> char* {
        char* p = base + off;
        off += (bytes + 255) & ~(size_t)255;
        return p;
    };
    float* bufA   = (float*)carve((size_t)N * H * 4);
    float* bufB   = (float*)carve((size_t)N * H * 4);
    float* bufC   = (float*)carve((size_t)N * H * 4);
    int*   csr    = (int*)carve((size_t)E * 4);
    int*   rowptr = (int*)carve((size_t)(N + 1) * 4);
    int*   cnts   = (int*)carve((size_t)3 * N * 4);   // indeg | outdeg | fill
    int*   indeg  = cnts;
    int*   outdeg = cnts + N;
    int*   fill   = cnts + 2 * N;
    float* W1lT   = (float*)carve((size_t)H * H * 4);
    float* W1rT   = (float*)carve((size_t)H * H * 4);
    float* W2lT   = (float*)carve((size_t)H * H * 4);
    float* W2rT   = (float*)carve((size_t)H * H * 4);
    float* W3lT   = (float*)carve((size_t)H * H * 4);
    float* W3rT   = (float*)carve((size_t)H * H * 4);
    float* Wh1T   = (float*)carve((size_t)64 * H * 4);
    (void)ws_size; (void)n_in; (void)out_size;

    // 1) CSR build (indexed by dst; stores src). Deterministic up to fp sum order.
    hipMemsetAsync(cnts, 0, (size_t)3 * N * 4, stream);
    count_kernel<<<(E + 255) / 256, 256, 0, stream>>>(src, dst, indeg, outdeg, E);
    scan_kernel<<<1, 1024, 0, stream>>>(indeg, rowptr, N);
    fill_kernel<<<(E + 255) / 256, 256, 0, stream>>>(src, dst, rowptr, fill, csr, E);

    // 2) weight transposes (tiny, L2-resident afterwards)
    transpose_kernel<<<(H * H + 255) / 256, 256, 0, stream>>>(W1l, W1lT, H, H);
    transpose_kernel<<<(H * H + 255) / 256, 256, 0, stream>>>(W1r, W1rT, H, H);
    transpose_kernel<<<(H * H + 255) / 256, 256, 0, stream>>>(W2l, W2lT, H, H);
    transpose_kernel<<<(H * H + 255) / 256, 256, 0, stream>>>(W2r, W2rT, H, H);
    transpose_kernel<<<(H * H + 255) / 256, 256, 0, stream>>>(W3l, W3lT, H, H);
    transpose_kernel<<<(H * H + 255) / 256, 256, 0, stream>>>(W3r, W3rT, H, H);
    transpose_kernel<<<(64 * H + 255) / 256, 256, 0, stream>>>(Wh1, Wh1T, 64, H);

    // 3) encoder -> bufA
    encoder_kernel<<<((size_t)N * 32 + 255) / 256, 256, 0, stream>>>(
        x, Wenc, benc, demb, outdeg, bufA, N);

    const int gAgg  = (N + 3) / 4;
    const int gGemm = (N + 31) / 32;

    // 4) layer 1: h1 = relu(sage(h))            A -> B -> C
    aggregate_kernel<<<gAgg, 256, 0, stream>>>(bufA, rowptr, csr, bufB, N);
    gemm_sage<false><<<gGemm, 256, 0, stream>>>(bufB, bufA, W1lT, W1rT, b1l, bufC, N);

    // 5) layer 2: h2 = relu(sage(h1)) + h1      C -> B -> A
    aggregate_kernel<<<gAgg, 256, 0, stream>>>(bufC, rowptr, csr, bufB, N);
    gemm_sage<true><<<gGemm, 256, 0, stream>>>(bufB, bufC, W2lT, W2rT, b2l, bufA, N);

    // 6) layer 3: h3 = relu(sage(h2)) + h2      A -> B -> C
    aggregate_kernel<<<gAgg, 256, 0, stream>>>(bufA, rowptr, csr, bufB, N);
    gemm_sage<true><<<gGemm, 256, 0, stream>>>(bufB, bufA, W3lT, W3rT, b3l, bufC, N);

    // 7) head -> d_out  [1, N]
    head_kernel<<<gAgg, 256, 0, stream>>>(bufC, Wh1T, bh1, Wh2, bh2, (float*)d_out, N);
}

// Round 3
// 568.838 us; speedup vs baseline: 1.2544x; 1.2544x over previous
//
#include <hip/hip_runtime.h>

// ---------------------------------------------------------------------------
// DCINet: 3-layer GraphSAGE (mean aggr) + degree embedding encoder + MLP head.
// N=50000, E=800000, H=128. All fp32 (threshold ~3.4e-4 forbids bf16 chain).
// R2: fused head into layer-3 GEMM, parallel scan, float4 LDS GEMM, 2-node/wave agg.
// ---------------------------------------------------------------------------

#define HDIM 128

// ---- CSR build ------------------------------------------------------------

__global__ void count_kernel(const int* __restrict__ src, const int* __restrict__ dst,
                             int* __restrict__ indeg, int* __restrict__ outdeg, int E) {
    int e = blockIdx.x * blockDim.x + threadIdx.x;
    if (e < E) {
        atomicAdd(&indeg[dst[e]], 1);
        atomicAdd(&outdeg[src[e]], 1);
    }
}

// scan1: per-1024-chunk sums. 256 threads, 4 ints each.
__global__ __launch_bounds__(256) void scan1_kernel(const int* __restrict__ indeg,
                                                    int* __restrict__ bsum, int n) {
    __shared__ int shw[4];
    const int tid = threadIdx.x;
    const int base = blockIdx.x * 1024 + tid * 4;
    int s = 0;
#pragma unroll
    for (int j = 0; j < 4; ++j) {
        int i = base + j;
        if (i < n) s += indeg[i];
    }
    // wave reduce
#pragma unroll
    for (int off = 32; off > 0; off >>= 1) s += __shfl_down(s, off, 64);
    if ((tid & 63) == 0) shw[tid >> 6] = s;
    __syncthreads();
    if (tid == 0) bsum[blockIdx.x] = shw[0] + shw[1] + shw[2] + shw[3];
}

// scan2: exclusive scan of nb (<=64) chunk sums, in place; writes row_ptr[n]=total.
__global__ void scan2_kernel(int* __restrict__ bsum, int* __restrict__ row_ptr,
                             int nb, int n) {
    int lane = threadIdx.x;
    if (nb <= 64) {
        int v = (lane < nb) ? bsum[lane] : 0;
        int orig = v;
#pragma unroll
        for (int off = 1; off < 64; off <<= 1) {
            int t = __shfl_up(v, off, 64);
            if (lane >= off) v += t;
        }
        if (lane < nb) bsum[lane] = v - orig;      // exclusive
        if (lane == nb - 1) row_ptr[n] = v;        // total
    } else if (lane == 0) {                        // safety fallback
        int run = 0;
        for (int i = 0; i < nb; ++i) { int t = bsum[i]; bsum[i] = run; run += t; }
        row_ptr[n] = run;
    }
}

// scan3: per-chunk exclusive scan + chunk offset -> row_ptr[0..n)
__global__ __launch_bounds__(256) void scan3_kernel(const int* __restrict__ indeg,
                                                    const int* __restrict__ bsum,
                                                    int* __restrict__ row_ptr, int n) {
    __shared__ int shw[4];
    const int tid = threadIdx.x;
    const int lane = tid & 63;
    const int w = tid >> 6;
    const int base = blockIdx.x * 1024 + tid * 4;
    int v[4];
    int s = 0;
#pragma unroll
    for (int j = 0; j < 4; ++j) {
        int i = base + j;
        v[j] = (i < n) ? indeg[i] : 0;
        s += v[j];
    }
    int incl = s;
#pragma unroll
    for (int off = 1; off < 64; off <<= 1) {
        int t = __shfl_up(incl, off, 64);
        if (lane >= off) incl += t;
    }
    if (lane == 63) shw[w] = incl;
    __syncthreads();
    int woff = 0;
#pragma unroll
    for (int j = 0; j < 4; ++j) if (j < w) woff += shw[j];
    int pfx = bsum[blockIdx.x] + woff + incl - s;   // exclusive prefix for v[0]
#pragma unroll
    for (int j = 0; j < 4; ++j) {
        int i = base + j;
        if (i < n) row_ptr[i] = pfx;
        pfx += v[j];
    }
}

__global__ void fill_kernel(const int* __restrict__ src, const int* __restrict__ dst,
                            const int* __restrict__ row_ptr, int* __restrict__ fill,
                            int* __restrict__ csr, int E) {
    int e = blockIdx.x * blockDim.x + threadIdx.x;
    if (e < E) {
        int d = dst[e];
        int pos = atomicAdd(&fill[d], 1);
        csr[row_ptr[d] + pos] = src[e];
    }
}

// ---- tiny weight transpose: in [R][C] -> out [C][R] -----------------------

__global__ void transpose_kernel(const float* __restrict__ in, float* __restrict__ out,
                                 int R, int C) {
    int idx = blockIdx.x * blockDim.x + threadIdx.x;
    if (idx >= R * C) return;
    int r = idx / C, c = idx % C;
    out[c * R + r] = in[idx];
}

// ---- encoder: h = relu(x*Wenc + benc + deg_emb[min(outdeg,199)]) -----------

__global__ void encoder_kernel(const float* __restrict__ x, const float* __restrict__ Wenc,
                               const float* __restrict__ benc, const float* __restrict__ demb,
                               const int* __restrict__ outdeg, float* __restrict__ h, int n) {
    int idx = blockIdx.x * blockDim.x + threadIdx.x;   // over n*32 float4s
    if (idx >= n * 32) return;
    int i = idx >> 5, c4 = idx & 31;
    int d = outdeg[i]; if (d > 199) d = 199;
    float xv = x[i];
    float4 w = ((const float4*)Wenc)[c4];
    float4 b = ((const float4*)benc)[c4];
    float4 e = ((const float4*)demb)[d * 32 + c4];
    float4 o;
    o.x = fmaxf(xv * w.x + b.x + e.x, 0.f);
    o.y = fmaxf(xv * w.y + b.y + e.y, 0.f);
    o.z = fmaxf(xv * w.z + b.z + e.z, 0.f);
    o.w = fmaxf(xv * w.w + b.w + e.w, 0.f);
    ((float4*)h)[(size_t)i * 32 + c4] = o;
}

// ---- mean aggregation: 2 nodes per wave (32 lanes each), float4 per lane ----

__global__ __launch_bounds__(256) void aggregate_kernel(const float* __restrict__ hin,
                                                        const int* __restrict__ row_ptr,
                                                        const int* __restrict__ csr,
                                                        float* __restrict__ agg, int n) {
    const int tid = threadIdx.x;
    const int pair = (tid >> 5);               // 0..7 half-waves per block
    const int i = blockIdx.x * 8 + pair;
    if (i >= n) return;
    const int l32 = tid & 31;
    const int beg = row_ptr[i], end = row_ptr[i + 1];
    float ax = 0.f, ay = 0.f, az = 0.f, aw = 0.f;
    int e = beg;
    for (; e + 1 < end; e += 2) {
        int s0 = csr[e], s1 = csr[e + 1];
        float4 a = *(const float4*)(hin + (size_t)s0 * HDIM + l32 * 4);
        float4 b = *(const float4*)(hin + (size_t)s1 * HDIM + l32 * 4);
        ax += a.x + b.x; ay += a.y + b.y; az += a.z + b.z; aw += a.w + b.w;
    }
    if (e < end) {
        int s = csr[e];
        float4 a = *(const float4*)(hin + (size_t)s * HDIM + l32 * 4);
        ax += a.x; ay += a.y; az += a.z; aw += a.w;
    }
    float c = (float)(end - beg);
    float inv = 1.f / fmaxf(c, 1.f);
    float4 o; o.x = ax * inv; o.y = ay * inv; o.z = az * inv; o.w = aw * inv;
    *(float4*)(agg + (size_t)i * HDIM + l32 * 4) = o;
}

// ---- fused SAGE linear (+ optional residual, + optional fused MLP head) ----
// 32 rows x 128 cols per block of 256 threads; thread = 4 rows x 4 cols.
// HEAD: rows are kept in LDS (sA reused) and the MLP head is computed in-block;
//       no h3 is written to global, only scores[N].

template <bool RES, bool HEAD>
__global__ __launch_bounds__(256) void gemm_sage(const float* __restrict__ agg,
                                                 const float* __restrict__ hin,
                                                 const float* __restrict__ WlT,
                                                 const float* __restrict__ WrT,
                                                 const float* __restrict__ bias,
                                                 float* __restrict__ out, int n,
                                                 const float* __restrict__ Wh1T,
                                                 const float* __restrict__ bh1,
                                                 const float* __restrict__ Wh2,
                                                 const float* __restrict__ bh2) {
    __shared__ float sA[32][HDIM];
    __shared__ float sH[32][HDIM];
    const int t = threadIdx.x;
    const int row0 = blockIdx.x * 32;
    for (int i = t; i < 32 * 32; i += 256) {        // 1024 float4 per matrix
        int r = i >> 5, c4 = i & 31;
        int gr = row0 + r; if (gr > n - 1) gr = n - 1;
        ((float4*)(&sA[r][0]))[c4] = ((const float4*)(agg + (size_t)gr * HDIM))[c4];
        ((float4*)(&sH[r][0]))[c4] = ((const float4*)(hin + (size_t)gr * HDIM))[c4];
    }
    __syncthreads();
    const int cg = t & 31;      // cols cg*4 .. cg*4+3
    const int rg = t >> 5;      // rows rg*4 .. rg*4+3
    float acc[4][4] = {};
    for (int k0 = 0; k0 < 128; k0 += 4) {
        float4 a4[4], h4[4];
#pragma unroll
        for (int r = 0; r < 4; ++r) {
            a4[r] = *(const float4*)(&sA[rg * 4 + r][k0]);   // broadcast b128
            h4[r] = *(const float4*)(&sH[rg * 4 + r][k0]);
        }
#pragma unroll
        for (int j = 0; j < 4; ++j) {
            float4 wl = ((const float4*)(WlT + (size_t)(k0 + j) * HDIM))[cg];
            float4 wr = ((const float4*)(WrT + (size_t)(k0 + j) * HDIM))[cg];
#pragma unroll
            for (int r = 0; r < 4; ++r) {
                float a = ((const float*)&a4[r])[j];
                float hh = ((const float*)&h4[r])[j];
                acc[r][0] += a * wl.x + hh * wr.x;
                acc[r][1] += a * wl.y + hh * wr.y;
                acc[r][2] += a * wl.z + hh * wr.z;
                acc[r][3] += a * wl.w + hh * wr.w;
            }
        }
    }
    float4 bv = ((const float4*)bias)[cg];

    if (!HEAD) {
#pragma unroll
        for (int r = 0; r < 4; ++r) {
            int row = row0 + rg * 4 + r;
            if (row >= n) continue;
            float4 o;
            o.x = fmaxf(acc[r][0] + bv.x, 0.f);
            o.y = fmaxf(acc[r][1] + bv.y, 0.f);
            o.z = fmaxf(acc[r][2] + bv.z, 0.f);
            o.w = fmaxf(acc[r][3] + bv.w, 0.f);
            if (RES) {
                float4 rv = ((const float4*)(&sH[rg * 4 + r][0]))[cg];
                o.x += rv.x; o.y += rv.y; o.z += rv.z; o.w += rv.w;
            }
            ((float4*)(out + (size_t)row * HDIM))[cg] = o;
        }
        return;
    }

    // ---- fused head: rows -> sA (reuse), then z=relu(h3@Wh1T+bh1), s=z@Wh2+bh2
    __syncthreads();                 // everyone done reading sA
#pragma unroll
    for (int r = 0; r < 4; ++r) {
        float4 o;
        o.x = fmaxf(acc[r][0] + bv.x, 0.f);
        o.y = fmaxf(acc[r][1] + bv.y, 0.f);
        o.z = fmaxf(acc[r][2] + bv.z, 0.f);
        o.w = fmaxf(acc[r][3] + bv.w, 0.f);
        if (RES) {
            float4 rv = ((const float4*)(&sH[rg * 4 + r][0]))[cg];
            o.x += rv.x; o.y += rv.y; o.z += rv.z; o.w += rv.w;
        }
        ((float4*)(&sA[rg * 4 + r][0]))[cg] = o;   // h3 tile into LDS
    }
    __syncthreads();

    const int zc = t & 63;          // z column 0..63
    const int g8 = t >> 6;          // row group: rows g8*8 .. g8*8+7
    const float bh1v = bh1[zc];
    float z[8];
#pragma unroll
    for (int r = 0; r < 8; ++r) z[r] = bh1v;
    for (int k0 = 0; k0 < 128; k0 += 8) {
        float w[8];
#pragma unroll
        for (int j = 0; j < 8; ++j) w[j] = Wh1T[(size_t)(k0 + j) * 64 + zc];
#pragma unroll
        for (int r = 0; r < 8; ++r) {
            float4 a = *(const float4*)(&sA[g8 * 8 + r][k0]);       // broadcast
            float4 b = *(const float4*)(&sA[g8 * 8 + r][k0 + 4]);
            z[r] += a.x * w[0] + a.y * w[1] + a.z * w[2] + a.w * w[3]
                  + b.x * w[4] + b.y * w[5] + b.z * w[6] + b.w * w[7];
        }
    }
    const float wh2 = Wh2[zc];
    const float bh2v = bh2[0];
#pragma unroll
    for (int r = 0; r < 8; ++r) {
        float p = fmaxf(z[r], 0.f) * wh2;
#pragma unroll
        for (int off = 32; off > 0; off >>= 1) p += __shfl_down(p, off, 64);
        int row = row0 + g8 * 8 + r;
        if ((t & 63) == 0 && row < n) out[row] = p + bh2v;
    }
}

// ---------------------------------------------------------------------------

extern "C" void kernel_launch(void* const* d_in, const int* in_sizes, int n_in,
                              void* d_out, int out_size, void* d_ws, size_t ws_size,
                              hipStream_t stream) {
    const int N = in_sizes[0];          // x is [N,1]
    const int E = in_sizes[1] / 2;      // edge_index [2,E]
    const int H = HDIM;

    const float* x    = (const float*)d_in[0];
    const int*   ei   = (const int*)d_in[1];
    const int*   src  = ei;
    const int*   dst  = ei + E;
    const float* Wenc = (const float*)d_in[2];
    const float* benc = (const float*)d_in[3];
    const float* demb = (const float*)d_in[4];
    const float* W1l  = (const float*)d_in[5];
    const float* b1l  = (const float*)d_in[6];
    const float* W1r  = (const float*)d_in[7];
    const float* W2l  = (const float*)d_in[8];
    const float* b2l  = (const float*)d_in[9];
    const float* W2r  = (const float*)d_in[10];
    const float* W3l  = (const float*)d_in[11];
    const float* b3l  = (const float*)d_in[12];
    const float* W3r  = (const float*)d_in[13];
    const float* Wh1  = (const float*)d_in[14];
    const float* bh1  = (const float*)d_in[15];
    const float* Wh2  = (const float*)d_in[16];
    const float* bh2  = (const float*)d_in[17];

    // workspace carve (256B aligned)
    size_t off = 0;
    char* base = (char*)d_ws;
    auto carve = [&](size_t bytes) -> char* {
        char* p = base + off;
        off += (bytes + 255) & ~(size_t)255;
        return p;
    };
    float* bufA   = (float*)carve((size_t)N * H * 4);
    float* bufB   = (float*)carve((size_t)N * H * 4);
    float* bufC   = (float*)carve((size_t)N * H * 4);
    int*   csr    = (int*)carve((size_t)E * 4);
    int*   rowptr = (int*)carve((size_t)(N + 1) * 4);
    int*   cnts   = (int*)carve((size_t)3 * N * 4);   // indeg | outdeg | fill
    int*   indeg  = cnts;
    int*   outdeg = cnts + N;
    int*   fill   = cnts + 2 * N;
    int*   bsum   = (int*)carve(4096);
    float* W1lT   = (float*)carve((size_t)H * H * 4);
    float* W1rT   = (float*)carve((size_t)H * H * 4);
    float* W2lT   = (float*)carve((size_t)H * H * 4);
    float* W2rT   = (float*)carve((size_t)H * H * 4);
    float* W3lT   = (float*)carve((size_t)H * H * 4);
    float* W3rT   = (float*)carve((size_t)H * H * 4);
    float* Wh1T   = (float*)carve((size_t)64 * H * 4);
    (void)ws_size; (void)n_in; (void)out_size;

    const int nb = (N + 1023) / 1024;   // scan chunks

    // 1) CSR build (indexed by dst; stores src). Deterministic up to fp sum order.
    hipMemsetAsync(cnts, 0, (size_t)3 * N * 4, stream);
    count_kernel<<<(E + 255) / 256, 256, 0, stream>>>(src, dst, indeg, outdeg, E);
    scan1_kernel<<<nb, 256, 0, stream>>>(indeg, bsum, N);
    scan2_kernel<<<1, 64, 0, stream>>>(bsum, rowptr, nb, N);
    scan3_kernel<<<nb, 256, 0, stream>>>(indeg, bsum, rowptr, N);
    fill_kernel<<<(E + 255) / 256, 256, 0, stream>>>(src, dst, rowptr, fill, csr, E);

    // 2) weight transposes (tiny, L2-resident afterwards)
    transpose_kernel<<<(H * H + 255) / 256, 256, 0, stream>>>(W1l, W1lT, H, H);
    transpose_kernel<<<(H * H + 255) / 256, 256, 0, stream>>>(W1r, W1rT, H, H);
    transpose_kernel<<<(H * H + 255) / 256, 256, 0, stream>>>(W2l, W2lT, H, H);
    transpose_kernel<<<(H * H + 255) / 256, 256, 0, stream>>>(W2r, W2rT, H, H);
    transpose_kernel<<<(H * H + 255) / 256, 256, 0, stream>>>(W3l, W3lT, H, H);
    transpose_kernel<<<(H * H + 255) / 256, 256, 0, stream>>>(W3r, W3rT, H, H);
    transpose_kernel<<<(64 * H + 255) / 256, 256, 0, stream>>>(Wh1, Wh1T, 64, H);

    // 3) encoder -> bufA
    encoder_kernel<<<((size_t)N * 32 + 255) / 256, 256, 0, stream>>>(
        x, Wenc, benc, demb, outdeg, bufA, N);

    const int gAgg  = (N + 7) / 8;
    const int gGemm = (N + 31) / 32;

    // 4) layer 1: h1 = relu(sage(h))            A -> B -> C
    aggregate_kernel<<<gAgg, 256, 0, stream>>>(bufA, rowptr, csr, bufB, N);
    gemm_sage<false, false><<<gGemm, 256, 0, stream>>>(bufB, bufA, W1lT, W1rT, b1l, bufC, N,
                                                       nullptr, nullptr, nullptr, nullptr);

    // 5) layer 2: h2 = relu(sage(h1)) + h1      C -> B -> A
    aggregate_kernel<<<gAgg, 256, 0, stream>>>(bufC, rowptr, csr, bufB, N);
    gemm_sage<true, false><<<gGemm, 256, 0, stream>>>(bufB, bufC, W2lT, W2rT, b2l, bufA, N,
                                                      nullptr, nullptr, nullptr, nullptr);

    // 6) layer 3 + head: scores = head(relu(sage(h2)) + h2)   A -> B -> d_out
    aggregate_kernel<<<gAgg, 256, 0, stream>>>(bufA, rowptr, csr, bufB, N);
    gemm_sage<true, true><<<gGemm, 256, 0, stream>>>(bufB, bufA, W3lT, W3rT, b3l,
                                                     (float*)d_out, N,
                                                     Wh1T, bh1, Wh2, bh2);
}

// Round 4
// 367.219 us; speedup vs baseline: 1.9432x; 1.5490x over previous
//
#include <hip/hip_runtime.h>

// ---------------------------------------------------------------------------
// DCINet: 3-layer GraphSAGE (mean aggr) + degree embedding encoder + MLP head.
// N=50000, E=800000, H=128.
// R3: bf16 intermediates + MFMA (mfma_f32_16x16x32_bf16) for the SAGE GEMMs,
//     fp32 accumulation / bias / residual / head. bf16 halves gather traffic.
// ---------------------------------------------------------------------------

#define HDIM 128

typedef __attribute__((ext_vector_type(8))) short short8;   // 8 bf16 (4 VGPR)
typedef __attribute__((ext_vector_type(4))) float f32x4;

__device__ inline float bf2f(unsigned short u) {
    union { unsigned int u; float f; } t; t.u = (unsigned int)u << 16; return t.f;
}
__device__ inline unsigned short f2bf(float f) {           // round-to-nearest-even
    union { float f; unsigned int u; } t; t.f = f;
    unsigned int u = t.u;
    return (unsigned short)((u + 0x7FFFu + ((u >> 16) & 1u)) >> 16);
}

// ---- CSR build ------------------------------------------------------------

__global__ void count_kernel(const int* __restrict__ src, const int* __restrict__ dst,
                             int* __restrict__ indeg, int* __restrict__ outdeg, int E) {
    int e = blockIdx.x * blockDim.x + threadIdx.x;
    if (e < E) {
        atomicAdd(&indeg[dst[e]], 1);
        atomicAdd(&outdeg[src[e]], 1);
    }
}

__global__ __launch_bounds__(256) void scan1_kernel(const int* __restrict__ indeg,
                                                    int* __restrict__ bsum, int n) {
    __shared__ int shw[4];
    const int tid = threadIdx.x;
    const int base = blockIdx.x * 1024 + tid * 4;
    int s = 0;
#pragma unroll
    for (int j = 0; j < 4; ++j) {
        int i = base + j;
        if (i < n) s += indeg[i];
    }
#pragma unroll
    for (int off = 32; off > 0; off >>= 1) s += __shfl_down(s, off, 64);
    if ((tid & 63) == 0) shw[tid >> 6] = s;
    __syncthreads();
    if (tid == 0) bsum[blockIdx.x] = shw[0] + shw[1] + shw[2] + shw[3];
}

__global__ void scan2_kernel(int* __restrict__ bsum, int* __restrict__ row_ptr,
                             int nb, int n) {
    int lane = threadIdx.x;
    if (nb <= 64) {
        int v = (lane < nb) ? bsum[lane] : 0;
        int orig = v;
#pragma unroll
        for (int off = 1; off < 64; off <<= 1) {
            int t = __shfl_up(v, off, 64);
            if (lane >= off) v += t;
        }
        if (lane < nb) bsum[lane] = v - orig;
        if (lane == nb - 1) row_ptr[n] = v;
    } else if (lane == 0) {
        int run = 0;
        for (int i = 0; i < nb; ++i) { int t = bsum[i]; bsum[i] = run; run += t; }
        row_ptr[n] = run;
    }
}

__global__ __launch_bounds__(256) void scan3_kernel(const int* __restrict__ indeg,
                                                    const int* __restrict__ bsum,
                                                    int* __restrict__ row_ptr, int n) {
    __shared__ int shw[4];
    const int tid = threadIdx.x;
    const int lane = tid & 63;
    const int w = tid >> 6;
    const int base = blockIdx.x * 1024 + tid * 4;
    int v[4];
    int s = 0;
#pragma unroll
    for (int j = 0; j < 4; ++j) {
        int i = base + j;
        v[j] = (i < n) ? indeg[i] : 0;
        s += v[j];
    }
    int incl = s;
#pragma unroll
    for (int off = 1; off < 64; off <<= 1) {
        int t = __shfl_up(incl, off, 64);
        if (lane >= off) incl += t;
    }
    if (lane == 63) shw[w] = incl;
    __syncthreads();
    int woff = 0;
#pragma unroll
    for (int j = 0; j < 4; ++j) if (j < w) woff += shw[j];
    int pfx = bsum[blockIdx.x] + woff + incl - s;
#pragma unroll
    for (int j = 0; j < 4; ++j) {
        int i = base + j;
        if (i < n) row_ptr[i] = pfx;
        pfx += v[j];
    }
}

__global__ void fill_kernel(const int* __restrict__ src, const int* __restrict__ dst,
                            const int* __restrict__ row_ptr, int* __restrict__ fill,
                            int* __restrict__ csr, int E) {
    int e = blockIdx.x * blockDim.x + threadIdx.x;
    if (e < E) {
        int d = dst[e];
        int pos = atomicAdd(&fill[d], 1);
        csr[row_ptr[d] + pos] = src[e];
    }
}

// ---- weight fp32 -> bf16 (6 matrices of 128x128, row-major kept) ----------

__global__ void wconv_kernel(const float* __restrict__ W1l, const float* __restrict__ W1r,
                             const float* __restrict__ W2l, const float* __restrict__ W2r,
                             const float* __restrict__ W3l, const float* __restrict__ W3r,
                             unsigned short* __restrict__ out) {
    int idx = blockIdx.x * 256 + threadIdx.x;     // 6*16384 total
    int m = idx >> 14, o = idx & 16383;
    const float* s;
    switch (m) {
        case 0: s = W1l; break; case 1: s = W1r; break;
        case 2: s = W2l; break; case 3: s = W2r; break;
        case 4: s = W3l; break; default: s = W3r; break;
    }
    out[idx] = f2bf(s[o]);
}

// ---- Wh1 [64][128] -> Wh1T [128][64] fp32 (head stays fp32) ----------------

__global__ void transpose_kernel(const float* __restrict__ in, float* __restrict__ out,
                                 int R, int C) {
    int idx = blockIdx.x * blockDim.x + threadIdx.x;
    if (idx >= R * C) return;
    int r = idx / C, c = idx % C;
    out[c * R + r] = in[idx];
}

// ---- encoder: h = relu(x*Wenc + benc + deg_emb[min(outdeg,199)]) -> bf16 ---
// 16 lanes per node, 8 cols per lane.

__global__ void encoder_kernel(const float* __restrict__ x, const float* __restrict__ Wenc,
                               const float* __restrict__ benc, const float* __restrict__ demb,
                               const int* __restrict__ outdeg,
                               unsigned short* __restrict__ h, int n) {
    int idx = blockIdx.x * blockDim.x + threadIdx.x;   // over n*16
    if (idx >= n * 16) return;
    int i = idx >> 4, g = idx & 15;                    // cols g*8 .. g*8+7
    int d = outdeg[i]; if (d > 199) d = 199;
    float xv = x[i];
    const float* wp = Wenc + g * 8;
    const float* bp = benc + g * 8;
    const float* ep = demb + (size_t)d * HDIM + g * 8;
    short8 o;
#pragma unroll
    for (int j = 0; j < 8; ++j)
        o[j] = (short)f2bf(fmaxf(xv * wp[j] + bp[j] + ep[j], 0.f));
    *(short8*)(h + (size_t)i * HDIM + g * 8) = o;
}

// ---- mean aggregation: 4 nodes per wave (16 lanes each), bf16 in/out -------

__global__ __launch_bounds__(256) void aggregate_kernel(const unsigned short* __restrict__ hin,
                                                        const int* __restrict__ row_ptr,
                                                        const int* __restrict__ csr,
                                                        unsigned short* __restrict__ agg, int n) {
    const int tid = threadIdx.x;
    const int i = blockIdx.x * 16 + (tid >> 4);
    if (i >= n) return;
    const int l16 = tid & 15;
    const int beg = row_ptr[i], end = row_ptr[i + 1];
    float a[8] = {};
    int e = beg;
    for (; e + 1 < end; e += 2) {
        int s0 = csr[e], s1 = csr[e + 1];
        short8 v0 = *(const short8*)(hin + (size_t)s0 * HDIM + l16 * 8);
        short8 v1 = *(const short8*)(hin + (size_t)s1 * HDIM + l16 * 8);
#pragma unroll
        for (int j = 0; j < 8; ++j)
            a[j] += bf2f((unsigned short)v0[j]) + bf2f((unsigned short)v1[j]);
    }
    if (e < end) {
        int s0 = csr[e];
        short8 v0 = *(const short8*)(hin + (size_t)s0 * HDIM + l16 * 8);
#pragma unroll
        for (int j = 0; j < 8; ++j) a[j] += bf2f((unsigned short)v0[j]);
    }
    float inv = 1.f / fmaxf((float)(end - beg), 1.f);
    short8 o;
#pragma unroll
    for (int j = 0; j < 8; ++j) o[j] = (short)f2bf(a[j] * inv);
    *(short8*)(agg + (size_t)i * HDIM + l16 * 8) = o;
}

// ---- MFMA SAGE linear: out = relu(agg@Wl^T + hin@Wr^T + b) (+res) (+head) --
// Block = 256 thr = 4 waves; wave = 16 rows x 128 cols; K=128.
// B-fragment reads row-major W directly: lane needs W[col][k..k+7] (contiguous).

template <bool RES, bool HEAD>
__global__ __launch_bounds__(256) void gemm_mfma(const unsigned short* __restrict__ agg,
                                                 const unsigned short* __restrict__ hin,
                                                 const unsigned short* __restrict__ Wl,
                                                 const unsigned short* __restrict__ Wr,
                                                 const float* __restrict__ bias,
                                                 unsigned short* __restrict__ outBf,
                                                 float* __restrict__ scores, int n,
                                                 const float* __restrict__ Wh1T,
                                                 const float* __restrict__ bh1,
                                                 const float* __restrict__ Wh2,
                                                 const float* __restrict__ bh2) {
    __shared__ float sOut[64][HDIM + 4];
    const int t = threadIdx.x;
    const int l = t & 63;
    const int wv = t >> 6;
    const int row0b = blockIdx.x * 64;
    const int row0 = row0b + wv * 16;
    const int lrow = min(row0 + (l & 15), n - 1);
    const int kg = (l >> 4) * 8;

    const unsigned short* ap = agg + (size_t)lrow * HDIM + kg;
    const unsigned short* hp = hin + (size_t)lrow * HDIM + kg;
    const unsigned short* wlp = Wl + (size_t)(l & 15) * HDIM + kg;
    const unsigned short* wrp = Wr + (size_t)(l & 15) * HDIM + kg;

    f32x4 acc[8] = {};
#pragma unroll
    for (int k0 = 0; k0 < 128; k0 += 32) {
        short8 aA = *(const short8*)(ap + k0);
        short8 aH = *(const short8*)(hp + k0);
#pragma unroll
        for (int ct = 0; ct < 8; ++ct) {
            short8 bl = *(const short8*)(wlp + (size_t)ct * 16 * HDIM + k0);
            short8 br = *(const short8*)(wrp + (size_t)ct * 16 * HDIM + k0);
            acc[ct] = __builtin_amdgcn_mfma_f32_16x16x32_bf16(aA, bl, acc[ct], 0, 0, 0);
            acc[ct] = __builtin_amdgcn_mfma_f32_16x16x32_bf16(aH, br, acc[ct], 0, 0, 0);
        }
    }

    // dump acc -> LDS: D lane mapping: col = l&15 (+ct*16), row = (l>>4)*4 + r
    const int drow = wv * 16 + (l >> 4) * 4;
    const int dcol = l & 15;
#pragma unroll
    for (int ct = 0; ct < 8; ++ct)
#pragma unroll
        for (int r = 0; r < 4; ++r)
            sOut[drow + r][ct * 16 + dcol] = acc[ct][r];
    __syncthreads();

    // epilogue: bias + relu + residual; write bf16 out (or back to LDS for head)
#pragma unroll
    for (int j = 0; j < 8; ++j) {
        int i = t + j * 256;                 // over 64*32 float4-groups
        int r = i >> 5, c4 = i & 31;
        int grow = row0b + r;
        float4 v = *(const float4*)&sOut[r][c4 * 4];
        float4 bv = ((const float4*)bias)[c4];
        v.x = fmaxf(v.x + bv.x, 0.f);
        v.y = fmaxf(v.y + bv.y, 0.f);
        v.z = fmaxf(v.z + bv.z, 0.f);
        v.w = fmaxf(v.w + bv.w, 0.f);
        if (RES) {
            int rrow = min(grow, n - 1);
            const unsigned short* rp = hin + (size_t)rrow * HDIM + c4 * 4;
            v.x += bf2f(rp[0]); v.y += bf2f(rp[1]);
            v.z += bf2f(rp[2]); v.w += bf2f(rp[3]);
        }
        if (HEAD) {
            *(float4*)&sOut[r][c4 * 4] = v;
        } else if (grow < n) {
            unsigned short o[4] = {f2bf(v.x), f2bf(v.y), f2bf(v.z), f2bf(v.w)};
            *(uint2*)(outBf + (size_t)grow * HDIM + c4 * 4) = *(const uint2*)o;
        }
    }
    if (!HEAD) return;

    // ---- fused fp32 head on the 64-row LDS tile ----
    __syncthreads();
    const int zc = t & 63;                  // z column 0..63
    const int grp = t >> 6;                 // rows grp*16 .. grp*16+15
    const float bh1v = bh1[zc];
    float z[16];
#pragma unroll
    for (int r = 0; r < 16; ++r) z[r] = bh1v;
    for (int k0 = 0; k0 < 128; k0 += 8) {
        float w[8];
#pragma unroll
        for (int j = 0; j < 8; ++j) w[j] = Wh1T[(size_t)(k0 + j) * 64 + zc];
#pragma unroll
        for (int r = 0; r < 16; ++r) {
            float4 a = *(const float4*)&sOut[grp * 16 + r][k0];      // broadcast
            float4 b = *(const float4*)&sOut[grp * 16 + r][k0 + 4];
            z[r] += a.x * w[0] + a.y * w[1] + a.z * w[2] + a.w * w[3]
                  + b.x * w[4] + b.y * w[5] + b.z * w[6] + b.w * w[7];
        }
    }
    const float wh2 = Wh2[zc];
    const float bh2v = bh2[0];
#pragma unroll
    for (int r = 0; r < 16; ++r) {
        float p = fmaxf(z[r], 0.f) * wh2;
#pragma unroll
        for (int off = 32; off > 0; off >>= 1) p += __shfl_down(p, off, 64);
        int row = row0b + grp * 16 + r;
        if ((t & 63) == 0 && row < n) scores[row] = p + bh2v;
    }
}

// ---------------------------------------------------------------------------

extern "C" void kernel_launch(void* const* d_in, const int* in_sizes, int n_in,
                              void* d_out, int out_size, void* d_ws, size_t ws_size,
                              hipStream_t stream) {
    const int N = in_sizes[0];
    const int E = in_sizes[1] / 2;
    const int H = HDIM;

    const float* x    = (const float*)d_in[0];
    const int*   ei   = (const int*)d_in[1];
    const int*   src  = ei;
    const int*   dst  = ei + E;
    const float* Wenc = (const float*)d_in[2];
    const float* benc = (const float*)d_in[3];
    const float* demb = (const float*)d_in[4];
    const float* W1l  = (const float*)d_in[5];
    const float* b1l  = (const float*)d_in[6];
    const float* W1r  = (const float*)d_in[7];
    const float* W2l  = (const float*)d_in[8];
    const float* b2l  = (const float*)d_in[9];
    const float* W2r  = (const float*)d_in[10];
    const float* W3l  = (const float*)d_in[11];
    const float* b3l  = (const float*)d_in[12];
    const float* W3r  = (const float*)d_in[13];
    const float* Wh1  = (const float*)d_in[14];
    const float* bh1  = (const float*)d_in[15];
    const float* Wh2  = (const float*)d_in[16];
    const float* bh2  = (const float*)d_in[17];

    size_t off = 0;
    char* base = (char*)d_ws;
    auto carve = [&](size_t bytes) -> char* {
        char* p = base + off;
        off += (bytes + 255) & ~(size_t)255;
        return p;
    };
    unsigned short* bufA = (unsigned short*)carve((size_t)N * H * 2);
    unsigned short* bufB = (unsigned short*)carve((size_t)N * H * 2);
    unsigned short* bufC = (unsigned short*)carve((size_t)N * H * 2);
    int*   csr    = (int*)carve((size_t)E * 4);
    int*   rowptr = (int*)carve((size_t)(N + 1) * 4);
    int*   cnts   = (int*)carve((size_t)3 * N * 4);
    int*   indeg  = cnts;
    int*   outdeg = cnts + N;
    int*   fill   = cnts + 2 * N;
    int*   bsum   = (int*)carve(4096);
    unsigned short* Wb = (unsigned short*)carve((size_t)6 * H * H * 2);
    float* Wh1T   = (float*)carve((size_t)64 * H * 4);
    (void)ws_size; (void)n_in; (void)out_size;

    unsigned short* W1lb = Wb;
    unsigned short* W1rb = Wb + 1 * H * H;
    unsigned short* W2lb = Wb + 2 * H * H;
    unsigned short* W2rb = Wb + 3 * H * H;
    unsigned short* W3lb = Wb + 4 * H * H;
    unsigned short* W3rb = Wb + 5 * H * H;

    const int nb = (N + 1023) / 1024;

    // 1) CSR build
    hipMemsetAsync(cnts, 0, (size_t)3 * N * 4, stream);
    count_kernel<<<(E + 255) / 256, 256, 0, stream>>>(src, dst, indeg, outdeg, E);
    scan1_kernel<<<nb, 256, 0, stream>>>(indeg, bsum, N);
    scan2_kernel<<<1, 64, 0, stream>>>(bsum, rowptr, nb, N);
    scan3_kernel<<<nb, 256, 0, stream>>>(indeg, bsum, rowptr, N);
    fill_kernel<<<(E + 255) / 256, 256, 0, stream>>>(src, dst, rowptr, fill, csr, E);

    // 2) weights: bf16 convert (row-major kept) + fp32 head transpose
    wconv_kernel<<<(6 * H * H) / 256, 256, 0, stream>>>(W1l, W1r, W2l, W2r, W3l, W3r, Wb);
    transpose_kernel<<<(64 * H + 255) / 256, 256, 0, stream>>>(Wh1, Wh1T, 64, H);

    // 3) encoder -> bufA (bf16)
    encoder_kernel<<<((size_t)N * 16 + 255) / 256, 256, 0, stream>>>(
        x, Wenc, benc, demb, outdeg, bufA, N);

    const int gAgg  = (N + 15) / 16;
    const int gGemm = (N + 63) / 64;

    // 4) layer 1: h1 = relu(sage(h))            A -> B -> C
    aggregate_kernel<<<gAgg, 256, 0, stream>>>(bufA, rowptr, csr, bufB, N);
    gemm_mfma<false, false><<<gGemm, 256, 0, stream>>>(bufB, bufA, W1lb, W1rb, b1l,
                                                       bufC, nullptr, N,
                                                       nullptr, nullptr, nullptr, nullptr);

    // 5) layer 2: h2 = relu(sage(h1)) + h1      C -> B -> A
    aggregate_kernel<<<gAgg, 256, 0, stream>>>(bufC, rowptr, csr, bufB, N);
    gemm_mfma<true, false><<<gGemm, 256, 0, stream>>>(bufB, bufC, W2lb, W2rb, b2l,
                                                      bufA, nullptr, N,
                                                      nullptr, nullptr, nullptr, nullptr);

    // 6) layer 3 + head: scores = head(relu(sage(h2)) + h2)   A -> B -> d_out
    aggregate_kernel<<<gAgg, 256, 0, stream>>>(bufA, rowptr, csr, bufB, N);
    gemm_mfma<true, true><<<gGemm, 256, 0, stream>>>(bufB, bufA, W3lb, W3rb, b3l,
                                                     nullptr, (float*)d_out, N,
                                                     Wh1T, bh1, Wh2, bh2);
}

// Round 5
// 311.797 us; speedup vs baseline: 2.2886x; 1.1778x over previous
//
#include <hip/hip_runtime.h>

// ---------------------------------------------------------------------------
// DCINet: 3-layer GraphSAGE (mean aggr) + degree embedding encoder + MLP head.
// N=50000, E=800000, H=128.
// R5: swapped-operand MFMA (4 consecutive out-cols per lane -> packed 8B
//     stores, no LDS epilogue), 32 rows/wave (2x weight amortization),
//     MFMA head kernel, 4-edge-unrolled aggregate.
// ---------------------------------------------------------------------------

#define HDIM 128

typedef __attribute__((ext_vector_type(8))) short short8;   // 8 bf16 (4 VGPR)
typedef __attribute__((ext_vector_type(4))) float f32x4;

__device__ inline float bf2f(unsigned short u) {
    union { unsigned int u; float f; } t; t.u = (unsigned int)u << 16; return t.f;
}
__device__ inline unsigned short f2bf(float f) {           // round-to-nearest-even
    union { float f; unsigned int u; } t; t.f = f;
    unsigned int u = t.u;
    return (unsigned short)((u + 0x7FFFu + ((u >> 16) & 1u)) >> 16);
}

// ---- CSR build ------------------------------------------------------------

__global__ void count_kernel(const int* __restrict__ src, const int* __restrict__ dst,
                             int* __restrict__ indeg, int* __restrict__ outdeg, int E) {
    int e = blockIdx.x * blockDim.x + threadIdx.x;
    if (e < E) {
        atomicAdd(&indeg[dst[e]], 1);
        atomicAdd(&outdeg[src[e]], 1);
    }
}

__global__ __launch_bounds__(256) void scan1_kernel(const int* __restrict__ indeg,
                                                    int* __restrict__ bsum, int n) {
    __shared__ int shw[4];
    const int tid = threadIdx.x;
    const int base = blockIdx.x * 1024 + tid * 4;
    int s = 0;
#pragma unroll
    for (int j = 0; j < 4; ++j) {
        int i = base + j;
        if (i < n) s += indeg[i];
    }
#pragma unroll
    for (int off = 32; off > 0; off >>= 1) s += __shfl_down(s, off, 64);
    if ((tid & 63) == 0) shw[tid >> 6] = s;
    __syncthreads();
    if (tid == 0) bsum[blockIdx.x] = shw[0] + shw[1] + shw[2] + shw[3];
}

__global__ void scan2_kernel(int* __restrict__ bsum, int* __restrict__ row_ptr,
                             int nb, int n) {
    int lane = threadIdx.x;
    if (nb <= 64) {
        int v = (lane < nb) ? bsum[lane] : 0;
        int orig = v;
#pragma unroll
        for (int off = 1; off < 64; off <<= 1) {
            int t = __shfl_up(v, off, 64);
            if (lane >= off) v += t;
        }
        if (lane < nb) bsum[lane] = v - orig;
        if (lane == nb - 1) row_ptr[n] = v;
    } else if (lane == 0) {
        int run = 0;
        for (int i = 0; i < nb; ++i) { int t = bsum[i]; bsum[i] = run; run += t; }
        row_ptr[n] = run;
    }
}

__global__ __launch_bounds__(256) void scan3_kernel(const int* __restrict__ indeg,
                                                    const int* __restrict__ bsum,
                                                    int* __restrict__ row_ptr, int n) {
    __shared__ int shw[4];
    const int tid = threadIdx.x;
    const int lane = tid & 63;
    const int w = tid >> 6;
    const int base = blockIdx.x * 1024 + tid * 4;
    int v[4];
    int s = 0;
#pragma unroll
    for (int j = 0; j < 4; ++j) {
        int i = base + j;
        v[j] = (i < n) ? indeg[i] : 0;
        s += v[j];
    }
    int incl = s;
#pragma unroll
    for (int off = 1; off < 64; off <<= 1) {
        int t = __shfl_up(incl, off, 64);
        if (lane >= off) incl += t;
    }
    if (lane == 63) shw[w] = incl;
    __syncthreads();
    int woff = 0;
#pragma unroll
    for (int j = 0; j < 4; ++j) if (j < w) woff += shw[j];
    int pfx = bsum[blockIdx.x] + woff + incl - s;
#pragma unroll
    for (int j = 0; j < 4; ++j) {
        int i = base + j;
        if (i < n) row_ptr[i] = pfx;
        pfx += v[j];
    }
}

__global__ void fill_kernel(const int* __restrict__ src, const int* __restrict__ dst,
                            const int* __restrict__ row_ptr, int* __restrict__ fill,
                            int* __restrict__ csr, int E) {
    int e = blockIdx.x * blockDim.x + threadIdx.x;
    if (e < E) {
        int d = dst[e];
        int pos = atomicAdd(&fill[d], 1);
        csr[row_ptr[d] + pos] = src[e];
    }
}

// ---- weight fp32 -> bf16: 6x[128][128] + Wh1[64][128], row-major kept ------

__global__ void wconv_kernel(const float* __restrict__ W1l, const float* __restrict__ W1r,
                             const float* __restrict__ W2l, const float* __restrict__ W2r,
                             const float* __restrict__ W3l, const float* __restrict__ W3r,
                             const float* __restrict__ Wh1,
                             unsigned short* __restrict__ out) {
    int idx = blockIdx.x * 256 + threadIdx.x;     // 6*16384 + 8192 = 106496 total
    const float* s;
    int o;
    if (idx < 98304) {
        int m = idx >> 14; o = idx & 16383;
        switch (m) {
            case 0: s = W1l; break; case 1: s = W1r; break;
            case 2: s = W2l; break; case 3: s = W2r; break;
            case 4: s = W3l; break; default: s = W3r; break;
        }
    } else {
        s = Wh1; o = idx - 98304;
    }
    out[idx] = f2bf(s[o]);
}

// ---- encoder: h = relu(x*Wenc + benc + deg_emb[min(outdeg,199)]) -> bf16 ---

__global__ void encoder_kernel(const float* __restrict__ x, const float* __restrict__ Wenc,
                               const float* __restrict__ benc, const float* __restrict__ demb,
                               const int* __restrict__ outdeg,
                               unsigned short* __restrict__ h, int n) {
    int idx = blockIdx.x * blockDim.x + threadIdx.x;   // over n*16
    if (idx >= n * 16) return;
    int i = idx >> 4, g = idx & 15;                    // cols g*8 .. g*8+7
    int d = outdeg[i]; if (d > 199) d = 199;
    float xv = x[i];
    const float* wp = Wenc + g * 8;
    const float* bp = benc + g * 8;
    const float* ep = demb + (size_t)d * HDIM + g * 8;
    short8 o;
#pragma unroll
    for (int j = 0; j < 8; ++j)
        o[j] = (short)f2bf(fmaxf(xv * wp[j] + bp[j] + ep[j], 0.f));
    *(short8*)(h + (size_t)i * HDIM + g * 8) = o;
}

// ---- mean aggregation: 4 nodes per wave (16 lanes each), 4-edge unroll -----

__global__ __launch_bounds__(256) void aggregate_kernel(const unsigned short* __restrict__ hin,
                                                        const int* __restrict__ row_ptr,
                                                        const int* __restrict__ csr,
                                                        unsigned short* __restrict__ agg, int n) {
    const int tid = threadIdx.x;
    const int i = blockIdx.x * 16 + (tid >> 4);
    if (i >= n) return;
    const int l16 = tid & 15;
    const int beg = row_ptr[i], end = row_ptr[i + 1];
    float a[8] = {};
    int e = beg;
    for (; e + 3 < end; e += 4) {
        int s0 = csr[e], s1 = csr[e + 1], s2 = csr[e + 2], s3 = csr[e + 3];
        short8 v0 = *(const short8*)(hin + (size_t)s0 * HDIM + l16 * 8);
        short8 v1 = *(const short8*)(hin + (size_t)s1 * HDIM + l16 * 8);
        short8 v2 = *(const short8*)(hin + (size_t)s2 * HDIM + l16 * 8);
        short8 v3 = *(const short8*)(hin + (size_t)s3 * HDIM + l16 * 8);
#pragma unroll
        for (int j = 0; j < 8; ++j)
            a[j] += (bf2f((unsigned short)v0[j]) + bf2f((unsigned short)v1[j]))
                  + (bf2f((unsigned short)v2[j]) + bf2f((unsigned short)v3[j]));
    }
    for (; e < end; ++e) {
        int s0 = csr[e];
        short8 v0 = *(const short8*)(hin + (size_t)s0 * HDIM + l16 * 8);
#pragma unroll
        for (int j = 0; j < 8; ++j) a[j] += bf2f((unsigned short)v0[j]);
    }
    float inv = 1.f / fmaxf((float)(end - beg), 1.f);
    short8 o;
#pragma unroll
    for (int j = 0; j < 8; ++j) o[j] = (short)f2bf(a[j] * inv);
    *(short8*)(agg + (size_t)i * HDIM + l16 * 8) = o;
}

// ---- MFMA SAGE linear: out = relu(agg@Wl^T + hin@Wr^T + b) (+res), bf16 out
// Swapped operands: D = W x X^T -> lane holds 4 CONSECUTIVE out-cols for one
// node (col quads), so the epilogue is packed 8B stores straight from regs.
// Block = 4 waves; wave = 32 rows (2 node-groups of 16) x 128 cols; K = 128.

template <bool RES>
__global__ __launch_bounds__(256) void gemm_mfma(const unsigned short* __restrict__ agg,
                                                 const unsigned short* __restrict__ hin,
                                                 const unsigned short* __restrict__ Wl,
                                                 const unsigned short* __restrict__ Wr,
                                                 const float* __restrict__ bias,
                                                 unsigned short* __restrict__ outBf, int n) {
    const int t = threadIdx.x;
    const int l = t & 63;
    const int wv = t >> 6;
    const int l16 = l & 15;
    const int q = l >> 4;                       // k-group / col-quad index 0..3
    const int row0 = blockIdx.x * 128 + wv * 32;
    const int node0 = min(row0 + l16, n - 1);
    const int node1 = min(row0 + 16 + l16, n - 1);

    const unsigned short* wlp = Wl + (size_t)l16 * HDIM + q * 8;
    const unsigned short* wrp = Wr + (size_t)l16 * HDIM + q * 8;
    const unsigned short* ap0 = agg + (size_t)node0 * HDIM + q * 8;
    const unsigned short* hp0 = hin + (size_t)node0 * HDIM + q * 8;
    const unsigned short* ap1 = agg + (size_t)node1 * HDIM + q * 8;
    const unsigned short* hp1 = hin + (size_t)node1 * HDIM + q * 8;

    f32x4 acc[2][8] = {};
#pragma unroll
    for (int k0 = 0; k0 < 128; k0 += 32) {
        short8 xa0 = *(const short8*)(ap0 + k0);
        short8 xh0 = *(const short8*)(hp0 + k0);
        short8 xa1 = *(const short8*)(ap1 + k0);
        short8 xh1 = *(const short8*)(hp1 + k0);
#pragma unroll
        for (int ct = 0; ct < 8; ++ct) {
            short8 bl = *(const short8*)(wlp + (size_t)ct * 16 * HDIM + k0);
            short8 br = *(const short8*)(wrp + (size_t)ct * 16 * HDIM + k0);
            acc[0][ct] = __builtin_amdgcn_mfma_f32_16x16x32_bf16(bl, xa0, acc[0][ct], 0, 0, 0);
            acc[0][ct] = __builtin_amdgcn_mfma_f32_16x16x32_bf16(br, xh0, acc[0][ct], 0, 0, 0);
            acc[1][ct] = __builtin_amdgcn_mfma_f32_16x16x32_bf16(bl, xa1, acc[1][ct], 0, 0, 0);
            acc[1][ct] = __builtin_amdgcn_mfma_f32_16x16x32_bf16(br, xh1, acc[1][ct], 0, 0, 0);
        }
    }

    // epilogue: lane holds cols ct*16 + q*4 + (0..3) of node ng; packed stores
#pragma unroll
    for (int ng = 0; ng < 2; ++ng) {
        int node = row0 + ng * 16 + l16;
        if (node >= n) continue;
        int cnode = min(node, n - 1);
#pragma unroll
        for (int ct = 0; ct < 8; ++ct) {
            const int c0 = ct * 16 + q * 4;
            float4 bv = *(const float4*)(bias + c0);
            float v0 = fmaxf(acc[ng][ct][0] + bv.x, 0.f);
            float v1 = fmaxf(acc[ng][ct][1] + bv.y, 0.f);
            float v2 = fmaxf(acc[ng][ct][2] + bv.z, 0.f);
            float v3 = fmaxf(acc[ng][ct][3] + bv.w, 0.f);
            if (RES) {
                const unsigned short* rp = hin + (size_t)cnode * HDIM + c0;
                uint2 rv = *(const uint2*)rp;
                v0 += bf2f((unsigned short)(rv.x & 0xFFFF));
                v1 += bf2f((unsigned short)(rv.x >> 16));
                v2 += bf2f((unsigned short)(rv.y & 0xFFFF));
                v3 += bf2f((unsigned short)(rv.y >> 16));
            }
            unsigned int o0 = (unsigned int)f2bf(v0) | ((unsigned int)f2bf(v1) << 16);
            unsigned int o1 = (unsigned int)f2bf(v2) | ((unsigned int)f2bf(v3) << 16);
            uint2 o; o.x = o0; o.y = o1;
            *(uint2*)(outBf + (size_t)node * HDIM + c0) = o;
        }
    }
}

// ---- MFMA head: scores = relu(h3@Wh1^T + bh1) @ Wh2 + bh2 ------------------
// Wave = 64 nodes (4 node-groups); z cols 0..63 (4 ct); fp32 after MFMA.

__global__ __launch_bounds__(256) void head_mfma(const unsigned short* __restrict__ h3,
                                                 const unsigned short* __restrict__ Wh1b,
                                                 const float* __restrict__ bh1,
                                                 const float* __restrict__ Wh2,
                                                 const float* __restrict__ bh2,
                                                 float* __restrict__ scores, int n) {
    const int t = threadIdx.x;
    const int l = t & 63;
    const int wv = t >> 6;
    const int l16 = l & 15;
    const int q = l >> 4;
    const int row0 = blockIdx.x * 256 + wv * 64;

    const unsigned short* whp = Wh1b + (size_t)l16 * HDIM + q * 8;

    f32x4 acc[4][4] = {};
#pragma unroll
    for (int k0 = 0; k0 < 128; k0 += 32) {
        short8 xf[4];
#pragma unroll
        for (int ng = 0; ng < 4; ++ng) {
            int node = min(row0 + ng * 16 + l16, n - 1);
            xf[ng] = *(const short8*)(h3 + (size_t)node * HDIM + q * 8 + k0);
        }
#pragma unroll
        for (int ct = 0; ct < 4; ++ct) {
            short8 wf = *(const short8*)(whp + (size_t)ct * 16 * HDIM + k0);
#pragma unroll
            for (int ng = 0; ng < 4; ++ng)
                acc[ng][ct] = __builtin_amdgcn_mfma_f32_16x16x32_bf16(wf, xf[ng], acc[ng][ct], 0, 0, 0);
        }
    }

    const float bh2v = bh2[0];
#pragma unroll
    for (int ng = 0; ng < 4; ++ng) {
        float p = 0.f;
#pragma unroll
        for (int ct = 0; ct < 4; ++ct) {
            const int c0 = ct * 16 + q * 4;
            float4 b1 = *(const float4*)(bh1 + c0);
            float4 w2 = *(const float4*)(Wh2 + c0);
            p += fmaxf(acc[ng][ct][0] + b1.x, 0.f) * w2.x;
            p += fmaxf(acc[ng][ct][1] + b1.y, 0.f) * w2.y;
            p += fmaxf(acc[ng][ct][2] + b1.z, 0.f) * w2.z;
            p += fmaxf(acc[ng][ct][3] + b1.w, 0.f) * w2.w;
        }
        p += __shfl_xor(p, 16, 64);
        p += __shfl_xor(p, 32, 64);
        int node = row0 + ng * 16 + l16;
        if (q == 0 && node < n) scores[node] = p + bh2v;
    }
}

// ---------------------------------------------------------------------------

extern "C" void kernel_launch(void* const* d_in, const int* in_sizes, int n_in,
                              void* d_out, int out_size, void* d_ws, size_t ws_size,
                              hipStream_t stream) {
    const int N = in_sizes[0];
    const int E = in_sizes[1] / 2;
    const int H = HDIM;

    const float* x    = (const float*)d_in[0];
    const int*   ei   = (const int*)d_in[1];
    const int*   src  = ei;
    const int*   dst  = ei + E;
    const float* Wenc = (const float*)d_in[2];
    const float* benc = (const float*)d_in[3];
    const float* demb = (const float*)d_in[4];
    const float* W1l  = (const float*)d_in[5];
    const float* b1l  = (const float*)d_in[6];
    const float* W1r  = (const float*)d_in[7];
    const float* W2l  = (const float*)d_in[8];
    const float* b2l  = (const float*)d_in[9];
    const float* W2r  = (const float*)d_in[10];
    const float* W3l  = (const float*)d_in[11];
    const float* b3l  = (const float*)d_in[12];
    const float* W3r  = (const float*)d_in[13];
    const float* Wh1  = (const float*)d_in[14];
    const float* bh1  = (const float*)d_in[15];
    const float* Wh2  = (const float*)d_in[16];
    const float* bh2  = (const float*)d_in[17];

    size_t off = 0;
    char* base = (char*)d_ws;
    auto carve = [&](size_t bytes) -> char* {
        char* p = base + off;
        off += (bytes + 255) & ~(size_t)255;
        return p;
    };
    unsigned short* bufA = (unsigned short*)carve((size_t)N * H * 2);
    unsigned short* bufB = (unsigned short*)carve((size_t)N * H * 2);
    unsigned short* bufC = (unsigned short*)carve((size_t)N * H * 2);
    int*   csr    = (int*)carve((size_t)E * 4);
    int*   rowptr = (int*)carve((size_t)(N + 1) * 4);
    int*   cnts   = (int*)carve((size_t)3 * N * 4);
    int*   indeg  = cnts;
    int*   outdeg = cnts + N;
    int*   fill   = cnts + 2 * N;
    int*   bsum   = (int*)carve(4096);
    unsigned short* Wb = (unsigned short*)carve((size_t)(6 * H * H + 64 * H) * 2);
    (void)ws_size; (void)n_in; (void)out_size;

    unsigned short* W1lb = Wb;
    unsigned short* W1rb = Wb + 1 * H * H;
    unsigned short* W2lb = Wb + 2 * H * H;
    unsigned short* W2rb = Wb + 3 * H * H;
    unsigned short* W3lb = Wb + 4 * H * H;
    unsigned short* W3rb = Wb + 5 * H * H;
    unsigned short* Wh1b = Wb + 6 * H * H;

    const int nb = (N + 1023) / 1024;

    // 1) CSR build
    hipMemsetAsync(cnts, 0, (size_t)3 * N * 4, stream);
    count_kernel<<<(E + 255) / 256, 256, 0, stream>>>(src, dst, indeg, outdeg, E);
    scan1_kernel<<<nb, 256, 0, stream>>>(indeg, bsum, N);
    scan2_kernel<<<1, 64, 0, stream>>>(bsum, rowptr, nb, N);
    scan3_kernel<<<nb, 256, 0, stream>>>(indeg, bsum, rowptr, N);
    fill_kernel<<<(E + 255) / 256, 256, 0, stream>>>(src, dst, rowptr, fill, csr, E);

    // 2) weights -> bf16 (row-major kept; includes Wh1)
    wconv_kernel<<<(6 * H * H + 64 * H) / 256, 256, 0, stream>>>(
        W1l, W1r, W2l, W2r, W3l, W3r, Wh1, Wb);

    // 3) encoder -> bufA (bf16)
    encoder_kernel<<<((size_t)N * 16 + 255) / 256, 256, 0, stream>>>(
        x, Wenc, benc, demb, outdeg, bufA, N);

    const int gAgg  = (N + 15) / 16;
    const int gGemm = (N + 127) / 128;
    const int gHead = (N + 255) / 256;

    // 4) layer 1: h1 = relu(sage(h))            A -> B -> C
    aggregate_kernel<<<gAgg, 256, 0, stream>>>(bufA, rowptr, csr, bufB, N);
    gemm_mfma<false><<<gGemm, 256, 0, stream>>>(bufB, bufA, W1lb, W1rb, b1l, bufC, N);

    // 5) layer 2: h2 = relu(sage(h1)) + h1      C -> B -> A
    aggregate_kernel<<<gAgg, 256, 0, stream>>>(bufC, rowptr, csr, bufB, N);
    gemm_mfma<true><<<gGemm, 256, 0, stream>>>(bufB, bufC, W2lb, W2rb, b2l, bufA, N);

    // 6) layer 3: h3 = relu(sage(h2)) + h2      A -> B -> C
    aggregate_kernel<<<gAgg, 256, 0, stream>>>(bufA, rowptr, csr, bufB, N);
    gemm_mfma<true><<<gGemm, 256, 0, stream>>>(bufB, bufA, W3lb, W3rb, b3l, bufC, N);

    // 7) head: scores = relu(h3@Wh1^T+bh1)@Wh2 + bh2   C -> d_out
    head_mfma<<<gHead, 256, 0, stream>>>(bufC, Wh1b, bh1, Wh2, bh2, (float*)d_out, N);
}

// Round 6
// 305.168 us; speedup vs baseline: 2.3383x; 1.0217x over previous
//
#include <hip/hip_runtime.h>

// ---------------------------------------------------------------------------
// DCINet: 3-layer GraphSAGE (mean aggr) + degree embedding encoder + MLP head.
// N=50000, E=800000, H=128.
// R6: de-contended CSR build — 32B-padded, 4-way-sharded atomic counters for
//     count/fill (deterministic edge->shard map), sumdeg prep kernel folds
//     shards into linear degrees + per-shard fill bases. GEMM/agg as R5.
// ---------------------------------------------------------------------------

#define HDIM 128
#define NS 4            // atomic shards
#define CPAD 8          // ints per counter slot (32 B = 1 write-through sector)

typedef __attribute__((ext_vector_type(8))) short short8;   // 8 bf16 (4 VGPR)
typedef __attribute__((ext_vector_type(4))) float f32x4;

__device__ inline float bf2f(unsigned short u) {
    union { unsigned int u; float f; } t; t.u = (unsigned int)u << 16; return t.f;
}
__device__ inline unsigned short f2bf(float f) {           // round-to-nearest-even
    union { float f; unsigned int u; } t; t.f = f;
    unsigned int u = t.u;
    return (unsigned short)((u + 0x7FFFu + ((u >> 16) & 1u)) >> 16);
}

__device__ inline size_t cslot(int s, int i, int n) {
    return ((size_t)s * n + i) * CPAD;
}

// ---- CSR build ------------------------------------------------------------

__global__ void count_kernel(const int* __restrict__ src, const int* __restrict__ dst,
                             int* __restrict__ cnt, int* __restrict__ ocnt, int E, int n) {
    int e = blockIdx.x * 256 + threadIdx.x;
    if (e < E) {
        int s = blockIdx.x & (NS - 1);
        atomicAdd(&cnt[cslot(s, dst[e], n)], 1);
        atomicAdd(&ocnt[cslot(s, src[e], n)], 1);
    }
}

// fold shards: cnt[s][i] -> prefix base (in place); indeg/outdeg -> linear
__global__ void sumdeg_kernel(int* __restrict__ cnt, const int* __restrict__ ocnt,
                              int* __restrict__ indeg, int* __restrict__ outdeg, int n) {
    int i = blockIdx.x * 256 + threadIdx.x;
    if (i >= n) return;
    int run = 0;
#pragma unroll
    for (int s = 0; s < NS; ++s) {
        size_t sl = cslot(s, i, n);
        int v = cnt[sl];
        cnt[sl] = run;          // per-shard base within this node's segment
        run += v;
    }
    indeg[i] = run;
    int od = 0;
#pragma unroll
    for (int s = 0; s < NS; ++s) od += ocnt[cslot(s, i, n)];
    outdeg[i] = od;
}

__global__ __launch_bounds__(256) void scan1_kernel(const int* __restrict__ indeg,
                                                    int* __restrict__ bsum, int n) {
    __shared__ int shw[4];
    const int tid = threadIdx.x;
    const int base = blockIdx.x * 1024 + tid * 4;
    int s = 0;
#pragma unroll
    for (int j = 0; j < 4; ++j) {
        int i = base + j;
        if (i < n) s += indeg[i];
    }
#pragma unroll
    for (int off = 32; off > 0; off >>= 1) s += __shfl_down(s, off, 64);
    if ((tid & 63) == 0) shw[tid >> 6] = s;
    __syncthreads();
    if (tid == 0) bsum[blockIdx.x] = shw[0] + shw[1] + shw[2] + shw[3];
}

__global__ void scan2_kernel(int* __restrict__ bsum, int* __restrict__ row_ptr,
                             int nb, int n) {
    int lane = threadIdx.x;
    if (nb <= 64) {
        int v = (lane < nb) ? bsum[lane] : 0;
        int orig = v;
#pragma unroll
        for (int off = 1; off < 64; off <<= 1) {
            int t = __shfl_up(v, off, 64);
            if (lane >= off) v += t;
        }
        if (lane < nb) bsum[lane] = v - orig;
        if (lane == nb - 1) row_ptr[n] = v;
    } else if (lane == 0) {
        int run = 0;
        for (int i = 0; i < nb; ++i) { int t = bsum[i]; bsum[i] = run; run += t; }
        row_ptr[n] = run;
    }
}

__global__ __launch_bounds__(256) void scan3_kernel(const int* __restrict__ indeg,
                                                    const int* __restrict__ bsum,
                                                    int* __restrict__ row_ptr, int n) {
    __shared__ int shw[4];
    const int tid = threadIdx.x;
    const int lane = tid & 63;
    const int w = tid >> 6;
    const int base = blockIdx.x * 1024 + tid * 4;
    int v[4];
    int s = 0;
#pragma unroll
    for (int j = 0; j < 4; ++j) {
        int i = base + j;
        v[j] = (i < n) ? indeg[i] : 0;
        s += v[j];
    }
    int incl = s;
#pragma unroll
    for (int off = 1; off < 64; off <<= 1) {
        int t = __shfl_up(incl, off, 64);
        if (lane >= off) incl += t;
    }
    if (lane == 63) shw[w] = incl;
    __syncthreads();
    int woff = 0;
#pragma unroll
    for (int j = 0; j < 4; ++j) if (j < w) woff += shw[j];
    int pfx = bsum[blockIdx.x] + woff + incl - s;
#pragma unroll
    for (int j = 0; j < 4; ++j) {
        int i = base + j;
        if (i < n) row_ptr[i] = pfx;
        pfx += v[j];
    }
}

// fill: same block->shard map as count; private per-shard cursors.
__global__ void fill_kernel(const int* __restrict__ src, const int* __restrict__ dst,
                            const int* __restrict__ row_ptr, const int* __restrict__ cnt,
                            int* __restrict__ fillc, int* __restrict__ csr, int E, int n) {
    int e = blockIdx.x * 256 + threadIdx.x;
    if (e < E) {
        int s = blockIdx.x & (NS - 1);
        int d = dst[e];
        size_t sl = cslot(s, d, n);
        int pos = atomicAdd(&fillc[sl], 1);
        csr[row_ptr[d] + cnt[sl] + pos] = src[e];
    }
}

// ---- weight fp32 -> bf16: 6x[128][128] + Wh1[64][128], row-major kept ------

__global__ void wconv_kernel(const float* __restrict__ W1l, const float* __restrict__ W1r,
                             const float* __restrict__ W2l, const float* __restrict__ W2r,
                             const float* __restrict__ W3l, const float* __restrict__ W3r,
                             const float* __restrict__ Wh1,
                             unsigned short* __restrict__ out) {
    int idx = blockIdx.x * 256 + threadIdx.x;     // 6*16384 + 8192 = 106496 total
    const float* s;
    int o;
    if (idx < 98304) {
        int m = idx >> 14; o = idx & 16383;
        switch (m) {
            case 0: s = W1l; break; case 1: s = W1r; break;
            case 2: s = W2l; break; case 3: s = W2r; break;
            case 4: s = W3l; break; default: s = W3r; break;
        }
    } else {
        s = Wh1; o = idx - 98304;
    }
    out[idx] = f2bf(s[o]);
}

// ---- encoder: h = relu(x*Wenc + benc + deg_emb[min(outdeg,199)]) -> bf16 ---

__global__ void encoder_kernel(const float* __restrict__ x, const float* __restrict__ Wenc,
                               const float* __restrict__ benc, const float* __restrict__ demb,
                               const int* __restrict__ outdeg,
                               unsigned short* __restrict__ h, int n) {
    int idx = blockIdx.x * blockDim.x + threadIdx.x;   // over n*16
    if (idx >= n * 16) return;
    int i = idx >> 4, g = idx & 15;                    // cols g*8 .. g*8+7
    int d = outdeg[i]; if (d > 199) d = 199;
    float xv = x[i];
    const float* wp = Wenc + g * 8;
    const float* bp = benc + g * 8;
    const float* ep = demb + (size_t)d * HDIM + g * 8;
    short8 o;
#pragma unroll
    for (int j = 0; j < 8; ++j)
        o[j] = (short)f2bf(fmaxf(xv * wp[j] + bp[j] + ep[j], 0.f));
    *(short8*)(h + (size_t)i * HDIM + g * 8) = o;
}

// ---- mean aggregation: 4 nodes per wave (16 lanes each), 4-edge unroll -----

__global__ __launch_bounds__(256) void aggregate_kernel(const unsigned short* __restrict__ hin,
                                                        const int* __restrict__ row_ptr,
                                                        const int* __restrict__ csr,
                                                        unsigned short* __restrict__ agg, int n) {
    const int tid = threadIdx.x;
    const int i = blockIdx.x * 16 + (tid >> 4);
    if (i >= n) return;
    const int l16 = tid & 15;
    const int beg = row_ptr[i], end = row_ptr[i + 1];
    float a[8] = {};
    int e = beg;
    for (; e + 3 < end; e += 4) {
        int s0 = csr[e], s1 = csr[e + 1], s2 = csr[e + 2], s3 = csr[e + 3];
        short8 v0 = *(const short8*)(hin + (size_t)s0 * HDIM + l16 * 8);
        short8 v1 = *(const short8*)(hin + (size_t)s1 * HDIM + l16 * 8);
        short8 v2 = *(const short8*)(hin + (size_t)s2 * HDIM + l16 * 8);
        short8 v3 = *(const short8*)(hin + (size_t)s3 * HDIM + l16 * 8);
#pragma unroll
        for (int j = 0; j < 8; ++j)
            a[j] += (bf2f((unsigned short)v0[j]) + bf2f((unsigned short)v1[j]))
                  + (bf2f((unsigned short)v2[j]) + bf2f((unsigned short)v3[j]));
    }
    for (; e < end; ++e) {
        int s0 = csr[e];
        short8 v0 = *(const short8*)(hin + (size_t)s0 * HDIM + l16 * 8);
#pragma unroll
        for (int j = 0; j < 8; ++j) a[j] += bf2f((unsigned short)v0[j]);
    }
    float inv = 1.f / fmaxf((float)(end - beg), 1.f);
    short8 o;
#pragma unroll
    for (int j = 0; j < 8; ++j) o[j] = (short)f2bf(a[j] * inv);
    *(short8*)(agg + (size_t)i * HDIM + l16 * 8) = o;
}

// ---- MFMA SAGE linear: out = relu(agg@Wl^T + hin@Wr^T + b) (+res), bf16 out
// Swapped operands: lane holds 4 consecutive out-cols per node -> packed 8B
// stores. Block = 4 waves; wave = 32 rows (2 node-groups of 16); K = 128.

template <bool RES>
__global__ __launch_bounds__(256) void gemm_mfma(const unsigned short* __restrict__ agg,
                                                 const unsigned short* __restrict__ hin,
                                                 const unsigned short* __restrict__ Wl,
                                                 const unsigned short* __restrict__ Wr,
                                                 const float* __restrict__ bias,
                                                 unsigned short* __restrict__ outBf, int n) {
    const int t = threadIdx.x;
    const int l = t & 63;
    const int wv = t >> 6;
    const int l16 = l & 15;
    const int q = l >> 4;                       // k-group / col-quad index 0..3
    const int row0 = blockIdx.x * 128 + wv * 32;
    const int node0 = min(row0 + l16, n - 1);
    const int node1 = min(row0 + 16 + l16, n - 1);

    const unsigned short* wlp = Wl + (size_t)l16 * HDIM + q * 8;
    const unsigned short* wrp = Wr + (size_t)l16 * HDIM + q * 8;
    const unsigned short* ap0 = agg + (size_t)node0 * HDIM + q * 8;
    const unsigned short* hp0 = hin + (size_t)node0 * HDIM + q * 8;
    const unsigned short* ap1 = agg + (size_t)node1 * HDIM + q * 8;
    const unsigned short* hp1 = hin + (size_t)node1 * HDIM + q * 8;

    f32x4 acc[2][8] = {};
#pragma unroll
    for (int k0 = 0; k0 < 128; k0 += 32) {
        short8 xa0 = *(const short8*)(ap0 + k0);
        short8 xh0 = *(const short8*)(hp0 + k0);
        short8 xa1 = *(const short8*)(ap1 + k0);
        short8 xh1 = *(const short8*)(hp1 + k0);
#pragma unroll
        for (int ct = 0; ct < 8; ++ct) {
            short8 bl = *(const short8*)(wlp + (size_t)ct * 16 * HDIM + k0);
            short8 br = *(const short8*)(wrp + (size_t)ct * 16 * HDIM + k0);
            acc[0][ct] = __builtin_amdgcn_mfma_f32_16x16x32_bf16(bl, xa0, acc[0][ct], 0, 0, 0);
            acc[0][ct] = __builtin_amdgcn_mfma_f32_16x16x32_bf16(br, xh0, acc[0][ct], 0, 0, 0);
            acc[1][ct] = __builtin_amdgcn_mfma_f32_16x16x32_bf16(bl, xa1, acc[1][ct], 0, 0, 0);
            acc[1][ct] = __builtin_amdgcn_mfma_f32_16x16x32_bf16(br, xh1, acc[1][ct], 0, 0, 0);
        }
    }

#pragma unroll
    for (int ng = 0; ng < 2; ++ng) {
        int node = row0 + ng * 16 + l16;
        if (node >= n) continue;
        int cnode = min(node, n - 1);
#pragma unroll
        for (int ct = 0; ct < 8; ++ct) {
            const int c0 = ct * 16 + q * 4;
            float4 bv = *(const float4*)(bias + c0);
            float v0 = fmaxf(acc[ng][ct][0] + bv.x, 0.f);
            float v1 = fmaxf(acc[ng][ct][1] + bv.y, 0.f);
            float v2 = fmaxf(acc[ng][ct][2] + bv.z, 0.f);
            float v3 = fmaxf(acc[ng][ct][3] + bv.w, 0.f);
            if (RES) {
                const unsigned short* rp = hin + (size_t)cnode * HDIM + c0;
                uint2 rv = *(const uint2*)rp;
                v0 += bf2f((unsigned short)(rv.x & 0xFFFF));
                v1 += bf2f((unsigned short)(rv.x >> 16));
                v2 += bf2f((unsigned short)(rv.y & 0xFFFF));
                v3 += bf2f((unsigned short)(rv.y >> 16));
            }
            unsigned int o0 = (unsigned int)f2bf(v0) | ((unsigned int)f2bf(v1) << 16);
            unsigned int o1 = (unsigned int)f2bf(v2) | ((unsigned int)f2bf(v3) << 16);
            uint2 o; o.x = o0; o.y = o1;
            *(uint2*)(outBf + (size_t)node * HDIM + c0) = o;
        }
    }
}

// ---- MFMA head: scores = relu(h3@Wh1^T + bh1) @ Wh2 + bh2 ------------------

__global__ __launch_bounds__(256) void head_mfma(const unsigned short* __restrict__ h3,
                                                 const unsigned short* __restrict__ Wh1b,
                                                 const float* __restrict__ bh1,
                                                 const float* __restrict__ Wh2,
                                                 const float* __restrict__ bh2,
                                                 float* __restrict__ scores, int n) {
    const int t = threadIdx.x;
    const int l = t & 63;
    const int wv = t >> 6;
    const int l16 = l & 15;
    const int q = l >> 4;
    const int row0 = blockIdx.x * 256 + wv * 64;

    const unsigned short* whp = Wh1b + (size_t)l16 * HDIM + q * 8;

    f32x4 acc[4][4] = {};
#pragma unroll
    for (int k0 = 0; k0 < 128; k0 += 32) {
        short8 xf[4];
#pragma unroll
        for (int ng = 0; ng < 4; ++ng) {
            int node = min(row0 + ng * 16 + l16, n - 1);
            xf[ng] = *(const short8*)(h3 + (size_t)node * HDIM + q * 8 + k0);
        }
#pragma unroll
        for (int ct = 0; ct < 4; ++ct) {
            short8 wf = *(const short8*)(whp + (size_t)ct * 16 * HDIM + k0);
#pragma unroll
            for (int ng = 0; ng < 4; ++ng)
                acc[ng][ct] = __builtin_amdgcn_mfma_f32_16x16x32_bf16(wf, xf[ng], acc[ng][ct], 0, 0, 0);
        }
    }

    const float bh2v = bh2[0];
#pragma unroll
    for (int ng = 0; ng < 4; ++ng) {
        float p = 0.f;
#pragma unroll
        for (int ct = 0; ct < 4; ++ct) {
            const int c0 = ct * 16 + q * 4;
            float4 b1 = *(const float4*)(bh1 + c0);
            float4 w2 = *(const float4*)(Wh2 + c0);
            p += fmaxf(acc[ng][ct][0] + b1.x, 0.f) * w2.x;
            p += fmaxf(acc[ng][ct][1] + b1.y, 0.f) * w2.y;
            p += fmaxf(acc[ng][ct][2] + b1.z, 0.f) * w2.z;
            p += fmaxf(acc[ng][ct][3] + b1.w, 0.f) * w2.w;
        }
        p += __shfl_xor(p, 16, 64);
        p += __shfl_xor(p, 32, 64);
        int node = row0 + ng * 16 + l16;
        if (q == 0 && node < n) scores[node] = p + bh2v;
    }
}

// ---------------------------------------------------------------------------

extern "C" void kernel_launch(void* const* d_in, const int* in_sizes, int n_in,
                              void* d_out, int out_size, void* d_ws, size_t ws_size,
                              hipStream_t stream) {
    const int N = in_sizes[0];
    const int E = in_sizes[1] / 2;
    const int H = HDIM;

    const float* x    = (const float*)d_in[0];
    const int*   ei   = (const int*)d_in[1];
    const int*   src  = ei;
    const int*   dst  = ei + E;
    const float* Wenc = (const float*)d_in[2];
    const float* benc = (const float*)d_in[3];
    const float* demb = (const float*)d_in[4];
    const float* W1l  = (const float*)d_in[5];
    const float* b1l  = (const float*)d_in[6];
    const float* W1r  = (const float*)d_in[7];
    const float* W2l  = (const float*)d_in[8];
    const float* b2l  = (const float*)d_in[9];
    const float* W2r  = (const float*)d_in[10];
    const float* W3l  = (const float*)d_in[11];
    const float* b3l  = (const float*)d_in[12];
    const float* W3r  = (const float*)d_in[13];
    const float* Wh1  = (const float*)d_in[14];
    const float* bh1  = (const float*)d_in[15];
    const float* Wh2  = (const float*)d_in[16];
    const float* bh2  = (const float*)d_in[17];

    size_t off = 0;
    char* base = (char*)d_ws;
    auto carve = [&](size_t bytes) -> char* {
        char* p = base + off;
        off += (bytes + 255) & ~(size_t)255;
        return p;
    };
    unsigned short* bufA = (unsigned short*)carve((size_t)N * H * 2);
    unsigned short* bufB = (unsigned short*)carve((size_t)N * H * 2);
    unsigned short* bufC = (unsigned short*)carve((size_t)N * H * 2);
    int*   csr    = (int*)carve((size_t)E * 4);
    int*   rowptr = (int*)carve((size_t)(N + 1) * 4);
    int*   indeg  = (int*)carve((size_t)N * 4);
    int*   outdeg = (int*)carve((size_t)N * 4);
    int*   bsum   = (int*)carve(4096);
    // padded+sharded atomic tables (contiguous so one memset clears all)
    size_t tblInts = (size_t)NS * N * CPAD;
    int*   cnt    = (int*)carve(tblInts * 3 * 4);
    int*   ocnt   = cnt + tblInts;
    int*   fillc  = cnt + 2 * tblInts;
    unsigned short* Wb = (unsigned short*)carve((size_t)(6 * H * H + 64 * H) * 2);
    (void)ws_size; (void)n_in; (void)out_size;

    unsigned short* W1lb = Wb;
    unsigned short* W1rb = Wb + 1 * H * H;
    unsigned short* W2lb = Wb + 2 * H * H;
    unsigned short* W2rb = Wb + 3 * H * H;
    unsigned short* W3lb = Wb + 4 * H * H;
    unsigned short* W3rb = Wb + 5 * H * H;
    unsigned short* Wh1b = Wb + 6 * H * H;

    const int nb = (N + 1023) / 1024;
    const int gE = (E + 255) / 256;

    // 1) CSR build (sharded/padded atomics)
    hipMemsetAsync(cnt, 0, tblInts * 3 * 4, stream);
    count_kernel<<<gE, 256, 0, stream>>>(src, dst, cnt, ocnt, E, N);
    sumdeg_kernel<<<(N + 255) / 256, 256, 0, stream>>>(cnt, ocnt, indeg, outdeg, N);
    scan1_kernel<<<nb, 256, 0, stream>>>(indeg, bsum, N);
    scan2_kernel<<<1, 64, 0, stream>>>(bsum, rowptr, nb, N);
    scan3_kernel<<<nb, 256, 0, stream>>>(indeg, bsum, rowptr, N);
    fill_kernel<<<gE, 256, 0, stream>>>(src, dst, rowptr, cnt, fillc, csr, E, N);

    // 2) weights -> bf16 (row-major kept; includes Wh1)
    wconv_kernel<<<(6 * H * H + 64 * H) / 256, 256, 0, stream>>>(
        W1l, W1r, W2l, W2r, W3l, W3r, Wh1, Wb);

    // 3) encoder -> bufA (bf16)
    encoder_kernel<<<((size_t)N * 16 + 255) / 256, 256, 0, stream>>>(
        x, Wenc, benc, demb, outdeg, bufA, N);

    const int gAgg  = (N + 15) / 16;
    const int gGemm = (N + 127) / 128;
    const int gHead = (N + 255) / 256;

    // 4) layer 1: h1 = relu(sage(h))            A -> B -> C
    aggregate_kernel<<<gAgg, 256, 0, stream>>>(bufA, rowptr, csr, bufB, N);
    gemm_mfma<false><<<gGemm, 256, 0, stream>>>(bufB, bufA, W1lb, W1rb, b1l, bufC, N);

    // 5) layer 2: h2 = relu(sage(h1)) + h1      C -> B -> A
    aggregate_kernel<<<gAgg, 256, 0, stream>>>(bufC, rowptr, csr, bufB, N);
    gemm_mfma<true><<<gGemm, 256, 0, stream>>>(bufB, bufC, W2lb, W2rb, b2l, bufA, N);

    // 6) layer 3: h3 = relu(sage(h2)) + h2      A -> B -> C
    aggregate_kernel<<<gAgg, 256, 0, stream>>>(bufA, rowptr, csr, bufB, N);
    gemm_mfma<true><<<gGemm, 256, 0, stream>>>(bufB, bufA, W3lb, W3rb, b3l, bufC, N);

    // 7) head: scores = relu(h3@Wh1^T+bh1)@Wh2 + bh2   C -> d_out
    head_mfma<<<gHead, 256, 0, stream>>>(bufC, Wh1b, bh1, Wh2, bh2, (float*)d_out, N);
}

// Round 7
// 224.998 us; speedup vs baseline: 3.1715x; 1.3563x over previous
//
#include <hip/hip_runtime.h>

// ---------------------------------------------------------------------------
// DCINet: 3-layer GraphSAGE (mean aggr) + degree embedding encoder + MLP head.
// N=50000, E=800000, H=128.
// R7: atomic-free CSR build via LDS counting sort (binhist -> scan -> scatter
//     -> per-bucket finalize). Memory-side global atomics were the wall
//     (26 G/s cap, R5/R6 evidence); LDS atomics + plain stores replace them.
//     u16 CSR. GEMM/head/encoder as R6.
// ---------------------------------------------------------------------------

#define HDIM 128
#define NB 256          // binning blocks
#define MAXBUK 512      // max buckets (N <= 65536)
#define SCH 4096        // elements per scan block (256 thr x 16)

typedef __attribute__((ext_vector_type(8))) short short8;   // 8 bf16 (4 VGPR)
typedef __attribute__((ext_vector_type(4))) float f32x4;

__device__ inline float bf2f(unsigned short u) {
    union { unsigned int u; float f; } t; t.u = (unsigned int)u << 16; return t.f;
}
__device__ inline unsigned short f2bf(float f) {           // round-to-nearest-even
    union { float f; unsigned int u; } t; t.f = f;
    unsigned int u = t.u;
    return (unsigned short)((u + 0x7FFFu + ((u >> 16) & 1u)) >> 16);
}

// ---- phase 1: per-block LDS histograms over buckets (dst and src keys) -----

__global__ __launch_bounds__(256) void binhist_kernel(const int* __restrict__ src,
                                                      const int* __restrict__ dst,
                                                      int* __restrict__ hist,
                                                      int E, int nbuk, int ec) {
    __shared__ int hD[MAXBUK], hS[MAXBUK];
    const int tid = threadIdx.x, bid = blockIdx.x;
    for (int i = tid; i < nbuk; i += 256) { hD[i] = 0; hS[i] = 0; }
    __syncthreads();
    const int s0 = bid * ec, s1 = min(E, s0 + ec);
    for (int e = s0 + tid; e < s1; e += 256) {
        atomicAdd(&hD[dst[e] >> 7], 1);
        atomicAdd(&hS[src[e] >> 7], 1);
    }
    __syncthreads();
    for (int i = tid; i < nbuk; i += 256) {
        hist[(size_t)i * NB + bid] = hD[i];
        hist[(size_t)(nbuk + i) * NB + bid] = hS[i];
    }
}

// ---- phase 2: exclusive scan over hist[L], L = 2*nbuk*NB (<= 262144) -------

__global__ __launch_bounds__(256) void hscan1_kernel(const int* __restrict__ a,
                                                     int* __restrict__ bsum, int L) {
    __shared__ int shw[4];
    const int tid = threadIdx.x;
    const int base = blockIdx.x * SCH + tid * 16;
    int s = 0;
#pragma unroll
    for (int j = 0; j < 16; ++j) { int i = base + j; if (i < L) s += a[i]; }
#pragma unroll
    for (int off = 32; off > 0; off >>= 1) s += __shfl_down(s, off, 64);
    if ((tid & 63) == 0) shw[tid >> 6] = s;
    __syncthreads();
    if (tid == 0) bsum[blockIdx.x] = shw[0] + shw[1] + shw[2] + shw[3];
}

__global__ void hscan2_kernel(int* __restrict__ bsum, int nb) {
    int lane = threadIdx.x;
    int v = (lane < nb) ? bsum[lane] : 0;
    int orig = v;
#pragma unroll
    for (int off = 1; off < 64; off <<= 1) {
        int t = __shfl_up(v, off, 64);
        if (lane >= off) v += t;
    }
    if (lane < nb) bsum[lane] = v - orig;      // exclusive
}

__global__ __launch_bounds__(256) void hscan3_kernel(const int* __restrict__ a,
                                                     const int* __restrict__ bsum,
                                                     int* __restrict__ out, int L) {
    __shared__ int shw[4];
    const int tid = threadIdx.x;
    const int lane = tid & 63;
    const int w = tid >> 6;
    const int base = blockIdx.x * SCH + tid * 16;
    int v[16];
    int s = 0;
#pragma unroll
    for (int j = 0; j < 16; ++j) {
        int i = base + j;
        v[j] = (i < L) ? a[i] : 0;
        s += v[j];
    }
    int incl = s;
#pragma unroll
    for (int off = 1; off < 64; off <<= 1) {
        int t = __shfl_up(incl, off, 64);
        if (lane >= off) incl += t;
    }
    if (lane == 63) shw[w] = incl;
    __syncthreads();
    int woff = 0;
#pragma unroll
    for (int j = 0; j < 4; ++j) if (j < w) woff += shw[j];
    int pfx = bsum[blockIdx.x] + woff + incl - s;
#pragma unroll
    for (int j = 0; j < 16; ++j) {
        int i = base + j;
        if (i < L) out[i] = pfx;
        pfx += v[j];
    }
}

// ---- phase 3: scatter edges into bucket-sorted arrays (LDS cursors) --------

__global__ __launch_bounds__(256) void binscatter_kernel(const int* __restrict__ src,
                                                         const int* __restrict__ dst,
                                                         const int* __restrict__ scanned,
                                                         unsigned int* __restrict__ binD,
                                                         unsigned char* __restrict__ binS,
                                                         int E, int nbuk, int ec) {
    __shared__ int curD[MAXBUK], curS[MAXBUK];
    const int tid = threadIdx.x, bid = blockIdx.x;
    for (int i = tid; i < nbuk; i += 256) {
        curD[i] = scanned[(size_t)i * NB + bid];
        curS[i] = scanned[(size_t)(nbuk + i) * NB + bid] - E;
    }
    __syncthreads();
    const int s0 = bid * ec, s1 = min(E, s0 + ec);
    for (int e = s0 + tid; e < s1; e += 256) {
        int s = src[e], d = dst[e];
        int pd = atomicAdd(&curD[d >> 7], 1);
        binD[pd] = (unsigned int)s | ((unsigned int)(d & 127) << 16);
        int ps = atomicAdd(&curS[s >> 7], 1);
        binS[ps] = (unsigned char)(s & 127);
    }
}

// ---- phase 4: per-bucket finalize -> rowptr, outdeg, u16 CSR ---------------

__global__ __launch_bounds__(256) void finalize_kernel(const unsigned int* __restrict__ binD,
                                                       const unsigned char* __restrict__ binS,
                                                       const int* __restrict__ scanned,
                                                       unsigned short* __restrict__ csr,
                                                       int* __restrict__ rowptr,
                                                       int* __restrict__ outdeg,
                                                       int E, int n, int nbuk) {
    __shared__ int cntD[128], cur[128], cntS[128];
    const int b = blockIdx.x, tid = threadIdx.x;
    if (tid < 128) { cntD[tid] = 0; cntS[tid] = 0; }
    __syncthreads();
    const int s0 = scanned[(size_t)b * NB];
    const int s1 = (b == nbuk - 1) ? E : scanned[(size_t)(b + 1) * NB];
    const int t0 = scanned[(size_t)(nbuk + b) * NB] - E;
    const int t1 = (b == nbuk - 1) ? E : scanned[(size_t)(nbuk + b + 1) * NB] - E;
    for (int e = s0 + tid; e < s1; e += 256) atomicAdd(&cntD[(binD[e] >> 16) & 127], 1);
    for (int e = t0 + tid; e < t1; e += 256) atomicAdd(&cntS[binS[e]], 1);
    __syncthreads();
    // inclusive scan of cntD -> cur
    if (tid < 128) cur[tid] = cntD[tid];
    __syncthreads();
    for (int off = 1; off < 128; off <<= 1) {
        int t = (tid < 128 && tid >= off) ? cur[tid - off] : 0;
        __syncthreads();
        if (tid < 128) cur[tid] += t;
        __syncthreads();
    }
    if (tid < 128) {
        int ex = cur[tid] - cntD[tid];           // exclusive base
        int node = b * 128 + tid;
        if (node < n) { rowptr[node] = s0 + ex; outdeg[node] = cntS[tid]; }
        cur[tid] = ex;                           // becomes cursor
    }
    __syncthreads();
    for (int e = s0 + tid; e < s1; e += 256) {
        unsigned int p = binD[e];
        int pos = atomicAdd(&cur[(p >> 16) & 127], 1);
        csr[s0 + pos] = (unsigned short)(p & 0xFFFFu);
    }
    if (b == 0 && tid == 0) rowptr[n] = E;
}

// ---- weight fp32 -> bf16: 6x[128][128] + Wh1[64][128], row-major kept ------

__global__ void wconv_kernel(const float* __restrict__ W1l, const float* __restrict__ W1r,
                             const float* __restrict__ W2l, const float* __restrict__ W2r,
                             const float* __restrict__ W3l, const float* __restrict__ W3r,
                             const float* __restrict__ Wh1,
                             unsigned short* __restrict__ out) {
    int idx = blockIdx.x * 256 + threadIdx.x;     // 6*16384 + 8192 = 106496 total
    const float* s;
    int o;
    if (idx < 98304) {
        int m = idx >> 14; o = idx & 16383;
        switch (m) {
            case 0: s = W1l; break; case 1: s = W1r; break;
            case 2: s = W2l; break; case 3: s = W2r; break;
            case 4: s = W3l; break; default: s = W3r; break;
        }
    } else {
        s = Wh1; o = idx - 98304;
    }
    out[idx] = f2bf(s[o]);
}

// ---- encoder: h = relu(x*Wenc + benc + deg_emb[min(outdeg,199)]) -> bf16 ---

__global__ void encoder_kernel(const float* __restrict__ x, const float* __restrict__ Wenc,
                               const float* __restrict__ benc, const float* __restrict__ demb,
                               const int* __restrict__ outdeg,
                               unsigned short* __restrict__ h, int n) {
    int idx = blockIdx.x * blockDim.x + threadIdx.x;   // over n*16
    if (idx >= n * 16) return;
    int i = idx >> 4, g = idx & 15;                    // cols g*8 .. g*8+7
    int d = outdeg[i]; if (d > 199) d = 199;
    float xv = x[i];
    const float* wp = Wenc + g * 8;
    const float* bp = benc + g * 8;
    const float* ep = demb + (size_t)d * HDIM + g * 8;
    short8 o;
#pragma unroll
    for (int j = 0; j < 8; ++j)
        o[j] = (short)f2bf(fmaxf(xv * wp[j] + bp[j] + ep[j], 0.f));
    *(short8*)(h + (size_t)i * HDIM + g * 8) = o;
}

// ---- mean aggregation: 4 nodes per wave (16 lanes each), 4-edge unroll -----

__global__ __launch_bounds__(256) void aggregate_kernel(const unsigned short* __restrict__ hin,
                                                        const int* __restrict__ row_ptr,
                                                        const unsigned short* __restrict__ csr,
                                                        unsigned short* __restrict__ agg, int n) {
    const int tid = threadIdx.x;
    const int i = blockIdx.x * 16 + (tid >> 4);
    if (i >= n) return;
    const int l16 = tid & 15;
    const int beg = row_ptr[i], end = row_ptr[i + 1];
    float a[8] = {};
    int e = beg;
    for (; e + 3 < end; e += 4) {
        int s0 = csr[e], s1 = csr[e + 1], s2 = csr[e + 2], s3 = csr[e + 3];
        short8 v0 = *(const short8*)(hin + (size_t)s0 * HDIM + l16 * 8);
        short8 v1 = *(const short8*)(hin + (size_t)s1 * HDIM + l16 * 8);
        short8 v2 = *(const short8*)(hin + (size_t)s2 * HDIM + l16 * 8);
        short8 v3 = *(const short8*)(hin + (size_t)s3 * HDIM + l16 * 8);
#pragma unroll
        for (int j = 0; j < 8; ++j)
            a[j] += (bf2f((unsigned short)v0[j]) + bf2f((unsigned short)v1[j]))
                  + (bf2f((unsigned short)v2[j]) + bf2f((unsigned short)v3[j]));
    }
    for (; e < end; ++e) {
        int s0 = csr[e];
        short8 v0 = *(const short8*)(hin + (size_t)s0 * HDIM + l16 * 8);
#pragma unroll
        for (int j = 0; j < 8; ++j) a[j] += bf2f((unsigned short)v0[j]);
    }
    float inv = 1.f / fmaxf((float)(end - beg), 1.f);
    short8 o;
#pragma unroll
    for (int j = 0; j < 8; ++j) o[j] = (short)f2bf(a[j] * inv);
    *(short8*)(agg + (size_t)i * HDIM + l16 * 8) = o;
}

// ---- MFMA SAGE linear: out = relu(agg@Wl^T + hin@Wr^T + b) (+res), bf16 out
// Swapped operands: lane holds 4 consecutive out-cols per node -> packed 8B
// stores. Block = 4 waves; wave = 32 rows (2 node-groups of 16); K = 128.

template <bool RES>
__global__ __launch_bounds__(256) void gemm_mfma(const unsigned short* __restrict__ agg,
                                                 const unsigned short* __restrict__ hin,
                                                 const unsigned short* __restrict__ Wl,
                                                 const unsigned short* __restrict__ Wr,
                                                 const float* __restrict__ bias,
                                                 unsigned short* __restrict__ outBf, int n) {
    const int t = threadIdx.x;
    const int l = t & 63;
    const int wv = t >> 6;
    const int l16 = l & 15;
    const int q = l >> 4;                       // k-group / col-quad index 0..3
    const int row0 = blockIdx.x * 128 + wv * 32;
    const int node0 = min(row0 + l16, n - 1);
    const int node1 = min(row0 + 16 + l16, n - 1);

    const unsigned short* wlp = Wl + (size_t)l16 * HDIM + q * 8;
    const unsigned short* wrp = Wr + (size_t)l16 * HDIM + q * 8;
    const unsigned short* ap0 = agg + (size_t)node0 * HDIM + q * 8;
    const unsigned short* hp0 = hin + (size_t)node0 * HDIM + q * 8;
    const unsigned short* ap1 = agg + (size_t)node1 * HDIM + q * 8;
    const unsigned short* hp1 = hin + (size_t)node1 * HDIM + q * 8;

    f32x4 acc[2][8] = {};
#pragma unroll
    for (int k0 = 0; k0 < 128; k0 += 32) {
        short8 xa0 = *(const short8*)(ap0 + k0);
        short8 xh0 = *(const short8*)(hp0 + k0);
        short8 xa1 = *(const short8*)(ap1 + k0);
        short8 xh1 = *(const short8*)(hp1 + k0);
#pragma unroll
        for (int ct = 0; ct < 8; ++ct) {
            short8 bl = *(const short8*)(wlp + (size_t)ct * 16 * HDIM + k0);
            short8 br = *(const short8*)(wrp + (size_t)ct * 16 * HDIM + k0);
            acc[0][ct] = __builtin_amdgcn_mfma_f32_16x16x32_bf16(bl, xa0, acc[0][ct], 0, 0, 0);
            acc[0][ct] = __builtin_amdgcn_mfma_f32_16x16x32_bf16(br, xh0, acc[0][ct], 0, 0, 0);
            acc[1][ct] = __builtin_amdgcn_mfma_f32_16x16x32_bf16(bl, xa1, acc[1][ct], 0, 0, 0);
            acc[1][ct] = __builtin_amdgcn_mfma_f32_16x16x32_bf16(br, xh1, acc[1][ct], 0, 0, 0);
        }
    }

#pragma unroll
    for (int ng = 0; ng < 2; ++ng) {
        int node = row0 + ng * 16 + l16;
        if (node >= n) continue;
        int cnode = min(node, n - 1);
#pragma unroll
        for (int ct = 0; ct < 8; ++ct) {
            const int c0 = ct * 16 + q * 4;
            float4 bv = *(const float4*)(bias + c0);
            float v0 = fmaxf(acc[ng][ct][0] + bv.x, 0.f);
            float v1 = fmaxf(acc[ng][ct][1] + bv.y, 0.f);
            float v2 = fmaxf(acc[ng][ct][2] + bv.z, 0.f);
            float v3 = fmaxf(acc[ng][ct][3] + bv.w, 0.f);
            if (RES) {
                const unsigned short* rp = hin + (size_t)cnode * HDIM + c0;
                uint2 rv = *(const uint2*)rp;
                v0 += bf2f((unsigned short)(rv.x & 0xFFFF));
                v1 += bf2f((unsigned short)(rv.x >> 16));
                v2 += bf2f((unsigned short)(rv.y & 0xFFFF));
                v3 += bf2f((unsigned short)(rv.y >> 16));
            }
            unsigned int o0 = (unsigned int)f2bf(v0) | ((unsigned int)f2bf(v1) << 16);
            unsigned int o1 = (unsigned int)f2bf(v2) | ((unsigned int)f2bf(v3) << 16);
            uint2 o; o.x = o0; o.y = o1;
            *(uint2*)(outBf + (size_t)node * HDIM + c0) = o;
        }
    }
}

// ---- MFMA head: scores = relu(h3@Wh1^T + bh1) @ Wh2 + bh2 ------------------

__global__ __launch_bounds__(256) void head_mfma(const unsigned short* __restrict__ h3,
                                                 const unsigned short* __restrict__ Wh1b,
                                                 const float* __restrict__ bh1,
                                                 const float* __restrict__ Wh2,
                                                 const float* __restrict__ bh2,
                                                 float* __restrict__ scores, int n) {
    const int t = threadIdx.x;
    const int l = t & 63;
    const int wv = t >> 6;
    const int l16 = l & 15;
    const int q = l >> 4;
    const int row0 = blockIdx.x * 256 + wv * 64;

    const unsigned short* whp = Wh1b + (size_t)l16 * HDIM + q * 8;

    f32x4 acc[4][4] = {};
#pragma unroll
    for (int k0 = 0; k0 < 128; k0 += 32) {
        short8 xf[4];
#pragma unroll
        for (int ng = 0; ng < 4; ++ng) {
            int node = min(row0 + ng * 16 + l16, n - 1);
            xf[ng] = *(const short8*)(h3 + (size_t)node * HDIM + q * 8 + k0);
        }
#pragma unroll
        for (int ct = 0; ct < 4; ++ct) {
            short8 wf = *(const short8*)(whp + (size_t)ct * 16 * HDIM + k0);
#pragma unroll
            for (int ng = 0; ng < 4; ++ng)
                acc[ng][ct] = __builtin_amdgcn_mfma_f32_16x16x32_bf16(wf, xf[ng], acc[ng][ct], 0, 0, 0);
        }
    }

    const float bh2v = bh2[0];
#pragma unroll
    for (int ng = 0; ng < 4; ++ng) {
        float p = 0.f;
#pragma unroll
        for (int ct = 0; ct < 4; ++ct) {
            const int c0 = ct * 16 + q * 4;
            float4 b1 = *(const float4*)(bh1 + c0);
            float4 w2 = *(const float4*)(Wh2 + c0);
            p += fmaxf(acc[ng][ct][0] + b1.x, 0.f) * w2.x;
            p += fmaxf(acc[ng][ct][1] + b1.y, 0.f) * w2.y;
            p += fmaxf(acc[ng][ct][2] + b1.z, 0.f) * w2.z;
            p += fmaxf(acc[ng][ct][3] + b1.w, 0.f) * w2.w;
        }
        p += __shfl_xor(p, 16, 64);
        p += __shfl_xor(p, 32, 64);
        int node = row0 + ng * 16 + l16;
        if (q == 0 && node < n) scores[node] = p + bh2v;
    }
}

// ---------------------------------------------------------------------------

extern "C" void kernel_launch(void* const* d_in, const int* in_sizes, int n_in,
                              void* d_out, int out_size, void* d_ws, size_t ws_size,
                              hipStream_t stream) {
    const int N = in_sizes[0];
    const int E = in_sizes[1] / 2;
    const int H = HDIM;

    const float* x    = (const float*)d_in[0];
    const int*   ei   = (const int*)d_in[1];
    const int*   src  = ei;
    const int*   dst  = ei + E;
    const float* Wenc = (const float*)d_in[2];
    const float* benc = (const float*)d_in[3];
    const float* demb = (const float*)d_in[4];
    const float* W1l  = (const float*)d_in[5];
    const float* b1l  = (const float*)d_in[6];
    const float* W1r  = (const float*)d_in[7];
    const float* W2l  = (const float*)d_in[8];
    const float* b2l  = (const float*)d_in[9];
    const float* W2r  = (const float*)d_in[10];
    const float* W3l  = (const float*)d_in[11];
    const float* b3l  = (const float*)d_in[12];
    const float* W3r  = (const float*)d_in[13];
    const float* Wh1  = (const float*)d_in[14];
    const float* bh1  = (const float*)d_in[15];
    const float* Wh2  = (const float*)d_in[16];
    const float* bh2  = (const float*)d_in[17];

    const int nbuk = (N + 127) >> 7;          // 391 for N=50000 (<= MAXBUK)
    const int L    = 2 * nbuk * NB;           // hist length
    const int nbk  = (L + SCH - 1) / SCH;     // scan chunks (49, <= 64)
    const int ec   = (E + NB - 1) / NB;       // edges per binning block

    size_t off = 0;
    char* base = (char*)d_ws;
    auto carve = [&](size_t bytes) -> char* {
        char* p = base + off;
        off += (bytes + 255) & ~(size_t)255;
        return p;
    };
    unsigned short* bufA = (unsigned short*)carve((size_t)N * H * 2);
    unsigned short* bufB = (unsigned short*)carve((size_t)N * H * 2);
    unsigned short* bufC = (unsigned short*)carve((size_t)N * H * 2);
    unsigned short* csr  = (unsigned short*)carve((size_t)E * 2);
    int*   rowptr  = (int*)carve((size_t)(N + 1) * 4);
    int*   outdeg  = (int*)carve((size_t)N * 4);
    int*   bsum    = (int*)carve(4096);
    int*   hist    = (int*)carve((size_t)L * 4);
    int*   scanned = (int*)carve((size_t)L * 4);
    unsigned int*  binD = (unsigned int*)carve((size_t)E * 4);
    unsigned char* binS = (unsigned char*)carve((size_t)E);
    unsigned short* Wb  = (unsigned short*)carve((size_t)(6 * H * H + 64 * H) * 2);
    (void)ws_size; (void)n_in; (void)out_size;

    unsigned short* W1lb = Wb;
    unsigned short* W1rb = Wb + 1 * H * H;
    unsigned short* W2lb = Wb + 2 * H * H;
    unsigned short* W2rb = Wb + 3 * H * H;
    unsigned short* W3lb = Wb + 4 * H * H;
    unsigned short* W3rb = Wb + 5 * H * H;
    unsigned short* Wh1b = Wb + 6 * H * H;

    // 1) CSR build — LDS counting sort, no global atomics
    binhist_kernel<<<NB, 256, 0, stream>>>(src, dst, hist, E, nbuk, ec);
    hscan1_kernel<<<nbk, 256, 0, stream>>>(hist, bsum, L);
    hscan2_kernel<<<1, 64, 0, stream>>>(bsum, nbk);
    hscan3_kernel<<<nbk, 256, 0, stream>>>(hist, bsum, scanned, L);
    binscatter_kernel<<<NB, 256, 0, stream>>>(src, dst, scanned, binD, binS, E, nbuk, ec);
    finalize_kernel<<<nbuk, 256, 0, stream>>>(binD, binS, scanned, csr, rowptr, outdeg,
                                              E, N, nbuk);

    // 2) weights -> bf16 (row-major kept; includes Wh1)
    wconv_kernel<<<(6 * H * H + 64 * H) / 256, 256, 0, stream>>>(
        W1l, W1r, W2l, W2r, W3l, W3r, Wh1, Wb);

    // 3) encoder -> bufA (bf16)
    encoder_kernel<<<((size_t)N * 16 + 255) / 256, 256, 0, stream>>>(
        x, Wenc, benc, demb, outdeg, bufA, N);

    const int gAgg  = (N + 15) / 16;
    const int gGemm = (N + 127) / 128;
    const int gHead = (N + 255) / 256;

    // 4) layer 1: h1 = relu(sage(h))            A -> B -> C
    aggregate_kernel<<<gAgg, 256, 0, stream>>>(bufA, rowptr, csr, bufB, N);
    gemm_mfma<false><<<gGemm, 256, 0, stream>>>(bufB, bufA, W1lb, W1rb, b1l, bufC, N);

    // 5) layer 2: h2 = relu(sage(h1)) + h1      C -> B -> A
    aggregate_kernel<<<gAgg, 256, 0, stream>>>(bufC, rowptr, csr, bufB, N);
    gemm_mfma<true><<<gGemm, 256, 0, stream>>>(bufB, bufC, W2lb, W2rb, b2l, bufA, N);

    // 6) layer 3: h3 = relu(sage(h2)) + h2      A -> B -> C
    aggregate_kernel<<<gAgg, 256, 0, stream>>>(bufA, rowptr, csr, bufB, N);
    gemm_mfma<true><<<gGemm, 256, 0, stream>>>(bufB, bufA, W3lb, W3rb, b3l, bufC, N);

    // 7) head: scores = relu(h3@Wh1^T+bh1)@Wh2 + bh2   C -> d_out
    head_mfma<<<gHead, 256, 0, stream>>>(bufC, Wh1b, bh1, Wh2, bh2, (float*)d_out, N);
}